// Round 1
// baseline (1866.694 us; speedup 1.0000x reference)
//
#include <hip/hip_runtime.h>
#include <math.h>

#define NBATCH 8
#define NPTS 4096
#define NPOINT 1024
#define NSAMPLE 32
#define PTDIM 67        // 3 xyz + 64 feat
#define BIGF 1e10f
#define PADG 132        // gfeat LDS row stride (128 + 4 pad)

// ---------------------------------------------------------------------------
// K0: repack xyz into SoA for coalesced access in ball-query / attention
// ---------------------------------------------------------------------------
__global__ __launch_bounds__(256) void repack_kernel(const float* __restrict__ pts,
    float* __restrict__ X, float* __restrict__ Y, float* __restrict__ Z) {
  int i = blockIdx.x * 256 + threadIdx.x;          // < NBATCH*NPTS
  const float* p = pts + (size_t)i * PTDIM;
  X[i] = p[0]; Y[i] = p[1]; Z[i] = p[2];
}

// ---------------------------------------------------------------------------
// K1: farthest point sampling. One block per batch, 512 threads, 8 pts/thread.
// Replicates jnp exactly: f32 ((dx*dx+dy*dy)+dz*dz), min, argmax first-index.
// One barrier per step: LDS atomicMax on monotonic (distbits<<32 | (4095-idx)).
// ---------------------------------------------------------------------------
__global__ __launch_bounds__(512) void fps_kernel(const float* __restrict__ pts,
                                                  int* __restrict__ cidx) {
  __shared__ float4 P[NPTS];
  __shared__ unsigned long long redslot[4];
  const int b = blockIdx.x, tid = threadIdx.x;
  const float* pb = pts + (size_t)b * NPTS * PTDIM;
  #pragma unroll
  for (int k = 0; k < 8; k++) {
    int j = tid + k * 512;
    const float* pj = pb + (size_t)j * PTDIM;
    P[j] = make_float4(pj[0], pj[1], pj[2], 0.0f);
  }
  if (tid == 0) { redslot[0] = 0; redslot[1] = 0; redslot[2] = 0; redslot[3] = 0; }
  float dl[8];
  #pragma unroll
  for (int k = 0; k < 8; k++) dl[k] = BIGF;
  __syncthreads();
  int f = 0;
  for (int t = 0; t < NPOINT; t++) {
    if (tid == 0) cidx[b * NPOINT + t] = f;        // emit BEFORE update (scan semantics)
    const float4 cp = P[f];
    float bv = -1.0f; int bi = 0;
    #pragma unroll
    for (int k = 0; k < 8; k++) {
      int j = tid + k * 512;                        // ascending j -> first-max kept
      float4 q = P[j];
      float dx = __fsub_rn(q.x, cp.x);
      float dy = __fsub_rn(q.y, cp.y);
      float dz = __fsub_rn(q.z, cp.z);
      float d = __fadd_rn(__fadd_rn(__fmul_rn(dx, dx), __fmul_rn(dy, dy)), __fmul_rn(dz, dz));
      float nd = fminf(dl[k], d);
      dl[k] = nd;
      if (nd > bv) { bv = nd; bi = j; }
    }
    #pragma unroll
    for (int off = 32; off >= 1; off >>= 1) {
      float ov = __shfl_xor(bv, off);
      int   oi = __shfl_xor(bi, off);
      if (ov > bv || (ov == bv && oi < bi)) { bv = ov; bi = oi; }
    }
    if ((tid & 63) == 0) {
      unsigned long long enc =
          ((unsigned long long)__float_as_uint(bv) << 32) |
          (unsigned long long)(unsigned)(NPTS - 1 - bi);   // bigger = smaller idx
      atomicMax(&redslot[t & 3], enc);
    }
    if (tid == 0) redslot[(t + 2) & 3] = 0;        // 2-ahead reset: race-free (barrier-separated)
    __syncthreads();
    f = NPTS - 1 - (int)(redslot[t & 3] & 0xFFFFFFFFull);
  }
}

// ---------------------------------------------------------------------------
// K2: 3-layer MLP over ALL points (MLP∘gather == gather∘MLP). Thread-per-row,
// weights in LDS (broadcast reads), fully unrolled so x/h stay in VGPRs.
// ---------------------------------------------------------------------------
__global__ __launch_bounds__(256, 2) void mlp_kernel(
    const float* __restrict__ pts,
    const float* __restrict__ W0, const float* __restrict__ B0, const float* __restrict__ G0, const float* __restrict__ E0,
    const float* __restrict__ W1, const float* __restrict__ B1, const float* __restrict__ G1, const float* __restrict__ E1,
    const float* __restrict__ W2, const float* __restrict__ B2, const float* __restrict__ G2, const float* __restrict__ E2,
    float* __restrict__ mfeat) {
  __shared__ float w0[64 * 64], w1[64 * 64], w2[128 * 64];
  __shared__ float bb0[64], ss0[64], ee0[64];
  __shared__ float bb1[64], ss1[64], ee1[64];
  __shared__ float bb2[128], ss2[128], ee2[128];
  const float INVS = 0.99999500003750f;            // 1/sqrt(1+1e-5)
  const int t = threadIdx.x;
  for (int i = t; i < 4096; i += 256) { w0[i] = W0[i]; w1[i] = W1[i]; }
  for (int i = t; i < 8192; i += 256) { w2[i] = W2[i]; }
  if (t < 64) {
    bb0[t] = B0[t]; ss0[t] = G0[t] * INVS; ee0[t] = E0[t];
    bb1[t] = B1[t]; ss1[t] = G1[t] * INVS; ee1[t] = E1[t];
  }
  if (t < 128) { bb2[t] = B2[t]; ss2[t] = G2[t] * INVS; ee2[t] = E2[t]; }
  __syncthreads();

  const size_t r = (size_t)blockIdx.x * 256 + t;   // row 0..32767
  const float* xr = pts + r * PTDIM + 3;
  float x[64];
  #pragma unroll
  for (int c = 0; c < 64; c++) x[c] = xr[c];

  float h1[64];
  #pragma unroll
  for (int o = 0; o < 64; o++) {
    float acc = bb0[o];
    #pragma unroll
    for (int c = 0; c < 64; c += 4) {
      float4 wv = *(const float4*)&w0[o * 64 + c];
      acc = fmaf(wv.x, x[c], acc);
      acc = fmaf(wv.y, x[c + 1], acc);
      acc = fmaf(wv.z, x[c + 2], acc);
      acc = fmaf(wv.w, x[c + 3], acc);
    }
    h1[o] = fmaxf(fmaf(acc, ss0[o], ee0[o]), 0.0f);
  }
  float h2[64];
  #pragma unroll
  for (int o = 0; o < 64; o++) {
    float acc = bb1[o];
    #pragma unroll
    for (int c = 0; c < 64; c += 4) {
      float4 wv = *(const float4*)&w1[o * 64 + c];
      acc = fmaf(wv.x, h1[c], acc);
      acc = fmaf(wv.y, h1[c + 1], acc);
      acc = fmaf(wv.z, h1[c + 2], acc);
      acc = fmaf(wv.w, h1[c + 3], acc);
    }
    h2[o] = fmaxf(fmaf(acc, ss1[o], ee1[o]), 0.0f);
  }
  float* orow = mfeat + r * 128;
  #pragma unroll
  for (int o = 0; o < 128; o += 4) {
    float a0 = bb2[o], a1 = bb2[o + 1], a2 = bb2[o + 2], a3 = bb2[o + 3];
    #pragma unroll
    for (int c = 0; c < 64; c += 4) {
      float4 wv0 = *(const float4*)&w2[(o    ) * 64 + c];
      float4 wv1 = *(const float4*)&w2[(o + 1) * 64 + c];
      float4 wv2 = *(const float4*)&w2[(o + 2) * 64 + c];
      float4 wv3 = *(const float4*)&w2[(o + 3) * 64 + c];
      a0 = fmaf(wv0.x, h2[c], a0); a0 = fmaf(wv0.y, h2[c+1], a0); a0 = fmaf(wv0.z, h2[c+2], a0); a0 = fmaf(wv0.w, h2[c+3], a0);
      a1 = fmaf(wv1.x, h2[c], a1); a1 = fmaf(wv1.y, h2[c+1], a1); a1 = fmaf(wv1.z, h2[c+2], a1); a1 = fmaf(wv1.w, h2[c+3], a1);
      a2 = fmaf(wv2.x, h2[c], a2); a2 = fmaf(wv2.y, h2[c+1], a2); a2 = fmaf(wv2.z, h2[c+2], a2); a2 = fmaf(wv2.w, h2[c+3], a2);
      a3 = fmaf(wv3.x, h2[c], a3); a3 = fmaf(wv3.y, h2[c+1], a3); a3 = fmaf(wv3.z, h2[c+2], a3); a3 = fmaf(wv3.w, h2[c+3], a3);
    }
    float4 ov;
    ov.x = fmaxf(fmaf(a0, ss2[o    ], ee2[o    ]), 0.0f);
    ov.y = fmaxf(fmaf(a1, ss2[o + 1], ee2[o + 1]), 0.0f);
    ov.z = fmaxf(fmaf(a2, ss2[o + 2], ee2[o + 2]), 0.0f);
    ov.w = fmaxf(fmaf(a3, ss2[o + 3], ee2[o + 3]), 0.0f);
    *(float4*)(orow + o) = ov;
  }
}

// ---------------------------------------------------------------------------
// K3: ball query. One wave per center. Exact f32 replication of
// d = ((-2*dot)+sc)+sx, mask d>0.04f, stable-(d,idx) 32-smallest, pad w/ first.
// ---------------------------------------------------------------------------
__global__ __launch_bounds__(256) void ballq_kernel(
    const float* __restrict__ X, const float* __restrict__ Y, const float* __restrict__ Z,
    const int* __restrict__ cidx, int* __restrict__ gidx) {
  __shared__ float dbuf[4][512];
  __shared__ int   ibuf[4][512];
  const int t = threadIdx.x;
  const int w = t >> 6, lane = t & 63;
  const int pc = blockIdx.x * 4 + w;               // 0..8191
  const int b = pc >> 10;
  const float* Xb = X + b * NPTS;
  const float* Yb = Y + b * NPTS;
  const float* Zb = Z + b * NPTS;
  const int cI = cidx[pc];
  const float cx = Xb[cI], cy = Yb[cI], cz = Zb[cI];
  const float sc = __fadd_rn(__fadd_rn(__fmul_rn(cx, cx), __fmul_rn(cy, cy)), __fmul_rn(cz, cz));
  const float R2 = 0.04f;                          // f32(0.2*0.2); below 0.04 -> same as np/jax
  int cnt = 0;                                     // wave-uniform
  for (int rr = 0; rr < 64; rr++) {
    int nI = rr * 64 + lane;
    float px = Xb[nI], py = Yb[nI], pz = Zb[nI];
    float dot = __fadd_rn(__fadd_rn(__fmul_rn(cx, px), __fmul_rn(cy, py)), __fmul_rn(cz, pz));
    float sx  = __fadd_rn(__fadd_rn(__fmul_rn(px, px), __fmul_rn(py, py)), __fmul_rn(pz, pz));
    float d   = __fadd_rn(__fadd_rn(__fmul_rn(-2.0f, dot), sc), sx);
    bool pred = !(d > R2);
    unsigned long long mask = __ballot(pred);
    if (pred) {
      int pos = cnt + (int)__popcll(mask & ((1ull << lane) - 1ull));
      if (pos < 512) { dbuf[w][pos] = d; ibuf[w][pos] = nI; }
    }
    cnt += (int)__popcll(mask);
  }
  const int K = cnt < 512 ? cnt : 512;
  float cd[8]; int ci[8];
  #pragma unroll
  for (int k = 0; k < 8; k++) {
    int pos = lane + 64 * k;
    if (pos < K) { cd[k] = dbuf[w][pos]; ci[k] = ibuf[w][pos]; }
    else         { cd[k] = INFINITY;     ci[k] = 0x7fffffff;  }
  }
  int first = 0;
  int* gout = gidx + pc * NSAMPLE;
  for (int it = 0; it < NSAMPLE; it++) {
    float bv = cd[0]; int bi = ci[0];
    #pragma unroll
    for (int k = 1; k < 8; k++)
      if (cd[k] < bv || (cd[k] == bv && ci[k] < bi)) { bv = cd[k]; bi = ci[k]; }
    #pragma unroll
    for (int off = 32; off >= 1; off >>= 1) {
      float ov = __shfl_xor(bv, off);
      int   oi = __shfl_xor(bi, off);
      if (ov < bv || (ov == bv && oi < bi)) { bv = ov; bi = oi; }
    }
    #pragma unroll
    for (int k = 0; k < 8; k++) if (ci[k] == bi) cd[k] = INFINITY;
    if (it == 0) first = bi;
    if (lane == 0) gout[it] = (it < K) ? bi : first;
  }
}

// ---------------------------------------------------------------------------
// K4: gather + attention. One block (256 thr) per center. Thread (n=t&31,
// q=t>>5) computes 16 logit channels; softmax over n via 32-lane shuffles.
// ---------------------------------------------------------------------------
__global__ __launch_bounds__(256, 3) void attn_kernel(
    const float* __restrict__ X, const float* __restrict__ Y, const float* __restrict__ Z,
    const float* __restrict__ mfeat, const int* __restrict__ cidx, const int* __restrict__ gidx,
    const float* __restrict__ a_att, float* __restrict__ out) {
  __shared__ float gf[NSAMPLE][PADG];              // gathered MLP feats
  __shared__ float delta[131][NSAMPLE];
  __shared__ float cf[128];
  __shared__ float gx[NSAMPLE], gy[NSAMPLE], gz[NSAMPLE];
  __shared__ float cxs[3];
  __shared__ int   gi_s[NSAMPLE];
  const int t = threadIdx.x;
  const int pc = blockIdx.x;                       // 0..8191
  const int b = pc >> 10;
  const int n = t & 31, q = t >> 5;                // q: 0..7, 16 channels each
  if (t < NSAMPLE) gi_s[t] = gidx[pc * NSAMPLE + t];
  const int cI = cidx[pc];
  if (t == 0) {
    cxs[0] = X[b * NPTS + cI]; cxs[1] = Y[b * NPTS + cI]; cxs[2] = Z[b * NPTS + cI];
  }
  if (t < 128) cf[t] = mfeat[((size_t)b * NPTS + cI) * 128 + t];
  __syncthreads();
  const int g = gi_s[n];
  const float* grow = mfeat + ((size_t)b * NPTS + g) * 128;
  #pragma unroll
  for (int k = 0; k < 4; k++) {
    float4 v = *(const float4*)(grow + q * 16 + 4 * k);
    *(float4*)&gf[n][q * 16 + 4 * k] = v;
  }
  if (t < NSAMPLE) {
    int gg = gi_s[t];
    gx[t] = X[b * NPTS + gg]; gy[t] = Y[b * NPTS + gg]; gz[t] = Z[b * NPTS + gg];
  }
  __syncthreads();
  if (t < NSAMPLE) {
    delta[0][t] = gx[t] - cxs[0];
    delta[1][t] = gy[t] - cxs[1];
    delta[2][t] = gz[t] - cxs[2];
  }
  #pragma unroll
  for (int k = 0; k < 16; k++) {
    int d = q * 16 + k;
    delta[3 + d][n] = gf[n][d] - cf[d];
  }
  __syncthreads();

  float acc[16];
  #pragma unroll
  for (int j = 0; j < 16; j++) acc[j] = 0.0f;
  for (int c = 0; c < 131; c++) {
    float dl = delta[c][n];                        // LDS broadcast
    const float* arow = a_att + c * 128 + q * 16;  // global, lane-dedup via cache
    #pragma unroll
    for (int k = 0; k < 4; k++) {
      float4 wv = *(const float4*)(arow + 4 * k);
      acc[4 * k + 0] = fmaf(dl, wv.x, acc[4 * k + 0]);
      acc[4 * k + 1] = fmaf(dl, wv.y, acc[4 * k + 1]);
      acc[4 * k + 2] = fmaf(dl, wv.z, acc[4 * k + 2]);
      acc[4 * k + 3] = fmaf(dl, wv.w, acc[4 * k + 3]);
    }
  }
  #pragma unroll
  for (int j = 0; j < 16; j++) acc[j] = acc[j] >= 0.0f ? acc[j] : 0.2f * acc[j];
  // softmax over n (32-lane subgroup; xor offsets <32 stay in group)
  float mx[16];
  #pragma unroll
  for (int j = 0; j < 16; j++) mx[j] = acc[j];
  #pragma unroll
  for (int off = 16; off >= 1; off >>= 1)
    #pragma unroll
    for (int j = 0; j < 16; j++) mx[j] = fmaxf(mx[j], __shfl_xor(mx[j], off));
  float e[16], s[16];
  #pragma unroll
  for (int j = 0; j < 16; j++) { e[j] = expf(acc[j] - mx[j]); s[j] = e[j]; }
  #pragma unroll
  for (int off = 16; off >= 1; off >>= 1)
    #pragma unroll
    for (int j = 0; j < 16; j++) s[j] += __shfl_xor(s[j], off);
  float gac[16];
  #pragma unroll
  for (int j = 0; j < 16; j++) gac[j] = (e[j] / s[j]) * gf[n][q * 16 + j];
  #pragma unroll
  for (int off = 16; off >= 1; off >>= 1)
    #pragma unroll
    for (int j = 0; j < 16; j++) gac[j] += __shfl_xor(gac[j], off);
  if (n == 0) {
    float* orow = out + (size_t)pc * 131;
    #pragma unroll
    for (int j = 0; j < 16; j++) orow[3 + q * 16 + j] = gac[j];
    if (q == 0) { orow[0] = cxs[0]; orow[1] = cxs[1]; orow[2] = cxs[2]; }
  }
}

// ---------------------------------------------------------------------------
extern "C" void kernel_launch(void* const* d_in, const int* in_sizes, int n_in,
                              void* d_out, int out_size, void* d_ws, size_t ws_size,
                              hipStream_t stream) {
  const float* points = (const float*)d_in[0];
  const float* W0 = (const float*)d_in[1];
  const float* B0 = (const float*)d_in[2];
  const float* G0 = (const float*)d_in[3];
  const float* E0 = (const float*)d_in[4];
  const float* W1 = (const float*)d_in[5];
  const float* B1 = (const float*)d_in[6];
  const float* G1 = (const float*)d_in[7];
  const float* E1 = (const float*)d_in[8];
  const float* W2 = (const float*)d_in[9];
  const float* B2 = (const float*)d_in[10];
  const float* G2 = (const float*)d_in[11];
  const float* E2 = (const float*)d_in[12];
  const float* Aatt = (const float*)d_in[13];
  float* out = (float*)d_out;

  // workspace layout (floats): mfeat | X | Y | Z | cidx | gidx  (~18.3 MB)
  float* mfeat = (float*)d_ws;
  float* Xw = mfeat + (size_t)NBATCH * NPTS * 128;
  float* Yw = Xw + NBATCH * NPTS;
  float* Zw = Yw + NBATCH * NPTS;
  int* cidxw = (int*)(Zw + NBATCH * NPTS);
  int* gidxw = cidxw + NBATCH * NPOINT;

  repack_kernel<<<NBATCH * NPTS / 256, 256, 0, stream>>>(points, Xw, Yw, Zw);
  fps_kernel<<<NBATCH, 512, 0, stream>>>(points, cidxw);
  mlp_kernel<<<NBATCH * NPTS / 256, 256, 0, stream>>>(points,
      W0, B0, G0, E0, W1, B1, G1, E1, W2, B2, G2, E2, mfeat);
  ballq_kernel<<<NBATCH * NPOINT / 4, 256, 0, stream>>>(Xw, Yw, Zw, cidxw, gidxw);
  attn_kernel<<<NBATCH * NPOINT, 256, 0, stream>>>(Xw, Yw, Zw, mfeat, cidxw, gidxw, Aatt, out);
}

// Round 2
// 1766.636 us; speedup vs baseline: 1.0566x; 1.0566x over previous
//
#include <hip/hip_runtime.h>
#include <math.h>

#define NBATCH 8
#define NPTS 4096
#define NPOINT 1024
#define NSAMPLE 32
#define PTDIM 67        // 3 xyz + 64 feat
#define BIGF 1e10f
#define PADG 132        // gfeat LDS row stride (128 + 4 pad)

// ---------------------------------------------------------------------------
// K0: repack xyz into SoA for coalesced access in ball-query / attention
// ---------------------------------------------------------------------------
__global__ __launch_bounds__(256) void repack_kernel(const float* __restrict__ pts,
    float* __restrict__ X, float* __restrict__ Y, float* __restrict__ Z) {
  int i = blockIdx.x * 256 + threadIdx.x;          // < NBATCH*NPTS
  const float* p = pts + (size_t)i * PTDIM;
  X[i] = p[0]; Y[i] = p[1]; Z[i] = p[2];
}

// ---------------------------------------------------------------------------
// K1: farthest point sampling. One block per batch, 512 threads, 8 pts/thread.
// v2: coords + running min-dist live in VGPRs (no per-step LDS point reads);
// argmax reduce = packed (f32bits<<32 | 4095-idx) u64 max via 6 shuffle
// levels + per-wave slot + ONE barrier + all-thread 8-slot reduce. No atomics,
// double-buffered slots (write buf[t&1] pre-barrier, read post-barrier; next
// step writes the other buffer => race-free with a single barrier per step).
// Exact f32 replication of jnp: ((dx*dx+dy*dy)+dz*dz), min, argmax first-idx.
// ---------------------------------------------------------------------------
__global__ __launch_bounds__(512) void fps_kernel(const float* __restrict__ pts,
                                                  int* __restrict__ cidx) {
  __shared__ float Px[NPTS], Py[NPTS], Pz[NPTS];   // broadcast copy (48 KB)
  __shared__ unsigned long long slots[2][8];
  const int b = blockIdx.x, tid = threadIdx.x;
  const int w = tid >> 6, lane = tid & 63;
  const float* pb = pts + (size_t)b * NPTS * PTDIM;
  float px[8], py[8], pz[8], dl[8];
  #pragma unroll
  for (int k = 0; k < 8; k++) {
    int j = tid + k * 512;
    const float* pj = pb + (size_t)j * PTDIM;
    float x = pj[0], y = pj[1], z = pj[2];
    px[k] = x; py[k] = y; pz[k] = z;
    Px[j] = x; Py[j] = y; Pz[j] = z;
    dl[k] = BIGF;
  }
  __syncthreads();
  int f = 0;
  for (int t = 0; t < NPOINT; t++) {
    if (tid == 0) cidx[b * NPOINT + t] = f;        // emit BEFORE update (scan semantics)
    const float cx = Px[f], cy = Py[f], cz = Pz[f];
    float bv = -1.0f; int bi = 0;
    #pragma unroll
    for (int k = 0; k < 8; k++) {
      float dx = __fsub_rn(px[k], cx);
      float dy = __fsub_rn(py[k], cy);
      float dz = __fsub_rn(pz[k], cz);
      float d = __fadd_rn(__fadd_rn(__fmul_rn(dx, dx), __fmul_rn(dy, dy)), __fmul_rn(dz, dz));
      float nd = fminf(dl[k], d);
      dl[k] = nd;
      if (nd > bv) { bv = nd; bi = tid + k * 512; }  // ascending j -> first-max kept
    }
    unsigned hi = __float_as_uint(bv);             // dist >= 0 -> bits monotone
    unsigned lo = (unsigned)(NPTS - 1 - bi);       // bigger = smaller idx
    #pragma unroll
    for (int off = 32; off >= 1; off >>= 1) {
      unsigned ohi = __shfl_xor(hi, off);
      unsigned olo = __shfl_xor(lo, off);
      if (ohi > hi || (ohi == hi && olo > lo)) { hi = ohi; lo = olo; }
    }
    if (lane == 0)
      slots[t & 1][w] = ((unsigned long long)hi << 32) | (unsigned long long)lo;
    __syncthreads();
    unsigned long long best = slots[t & 1][0];
    #pragma unroll
    for (int i = 1; i < 8; i++) {
      unsigned long long o = slots[t & 1][i];
      if (o > best) best = o;
    }
    f = NPTS - 1 - (int)(best & 0xFFFFFFFFull);
  }
}

// ---------------------------------------------------------------------------
// K2: 3-layer MLP over ALL points (MLP∘gather == gather∘MLP). Thread-per-row,
// weights in LDS (broadcast reads), fully unrolled so x/h stay in VGPRs.
// ---------------------------------------------------------------------------
__global__ __launch_bounds__(256, 2) void mlp_kernel(
    const float* __restrict__ pts,
    const float* __restrict__ W0, const float* __restrict__ B0, const float* __restrict__ G0, const float* __restrict__ E0,
    const float* __restrict__ W1, const float* __restrict__ B1, const float* __restrict__ G1, const float* __restrict__ E1,
    const float* __restrict__ W2, const float* __restrict__ B2, const float* __restrict__ G2, const float* __restrict__ E2,
    float* __restrict__ mfeat) {
  __shared__ float w0[64 * 64], w1[64 * 64], w2[128 * 64];
  __shared__ float bb0[64], ss0[64], ee0[64];
  __shared__ float bb1[64], ss1[64], ee1[64];
  __shared__ float bb2[128], ss2[128], ee2[128];
  const float INVS = 0.99999500003750f;            // 1/sqrt(1+1e-5)
  const int t = threadIdx.x;
  for (int i = t; i < 4096; i += 256) { w0[i] = W0[i]; w1[i] = W1[i]; }
  for (int i = t; i < 8192; i += 256) { w2[i] = W2[i]; }
  if (t < 64) {
    bb0[t] = B0[t]; ss0[t] = G0[t] * INVS; ee0[t] = E0[t];
    bb1[t] = B1[t]; ss1[t] = G1[t] * INVS; ee1[t] = E1[t];
  }
  if (t < 128) { bb2[t] = B2[t]; ss2[t] = G2[t] * INVS; ee2[t] = E2[t]; }
  __syncthreads();

  const size_t r = (size_t)blockIdx.x * 256 + t;   // row 0..32767
  const float* xr = pts + r * PTDIM + 3;
  float x[64];
  #pragma unroll
  for (int c = 0; c < 64; c++) x[c] = xr[c];

  float h1[64];
  #pragma unroll
  for (int o = 0; o < 64; o++) {
    float acc = bb0[o];
    #pragma unroll
    for (int c = 0; c < 64; c += 4) {
      float4 wv = *(const float4*)&w0[o * 64 + c];
      acc = fmaf(wv.x, x[c], acc);
      acc = fmaf(wv.y, x[c + 1], acc);
      acc = fmaf(wv.z, x[c + 2], acc);
      acc = fmaf(wv.w, x[c + 3], acc);
    }
    h1[o] = fmaxf(fmaf(acc, ss0[o], ee0[o]), 0.0f);
  }
  float h2[64];
  #pragma unroll
  for (int o = 0; o < 64; o++) {
    float acc = bb1[o];
    #pragma unroll
    for (int c = 0; c < 64; c += 4) {
      float4 wv = *(const float4*)&w1[o * 64 + c];
      acc = fmaf(wv.x, h1[c], acc);
      acc = fmaf(wv.y, h1[c + 1], acc);
      acc = fmaf(wv.z, h1[c + 2], acc);
      acc = fmaf(wv.w, h1[c + 3], acc);
    }
    h2[o] = fmaxf(fmaf(acc, ss1[o], ee1[o]), 0.0f);
  }
  float* orow = mfeat + r * 128;
  #pragma unroll
  for (int o = 0; o < 128; o += 4) {
    float a0 = bb2[o], a1 = bb2[o + 1], a2 = bb2[o + 2], a3 = bb2[o + 3];
    #pragma unroll
    for (int c = 0; c < 64; c += 4) {
      float4 wv0 = *(const float4*)&w2[(o    ) * 64 + c];
      float4 wv1 = *(const float4*)&w2[(o + 1) * 64 + c];
      float4 wv2 = *(const float4*)&w2[(o + 2) * 64 + c];
      float4 wv3 = *(const float4*)&w2[(o + 3) * 64 + c];
      a0 = fmaf(wv0.x, h2[c], a0); a0 = fmaf(wv0.y, h2[c+1], a0); a0 = fmaf(wv0.z, h2[c+2], a0); a0 = fmaf(wv0.w, h2[c+3], a0);
      a1 = fmaf(wv1.x, h2[c], a1); a1 = fmaf(wv1.y, h2[c+1], a1); a1 = fmaf(wv1.z, h2[c+2], a1); a1 = fmaf(wv1.w, h2[c+3], a1);
      a2 = fmaf(wv2.x, h2[c], a2); a2 = fmaf(wv2.y, h2[c+1], a2); a2 = fmaf(wv2.z, h2[c+2], a2); a2 = fmaf(wv2.w, h2[c+3], a2);
      a3 = fmaf(wv3.x, h2[c], a3); a3 = fmaf(wv3.y, h2[c+1], a3); a3 = fmaf(wv3.z, h2[c+2], a3); a3 = fmaf(wv3.w, h2[c+3], a3);
    }
    float4 ov;
    ov.x = fmaxf(fmaf(a0, ss2[o    ], ee2[o    ]), 0.0f);
    ov.y = fmaxf(fmaf(a1, ss2[o + 1], ee2[o + 1]), 0.0f);
    ov.z = fmaxf(fmaf(a2, ss2[o + 2], ee2[o + 2]), 0.0f);
    ov.w = fmaxf(fmaf(a3, ss2[o + 3], ee2[o + 3]), 0.0f);
    *(float4*)(orow + o) = ov;
  }
}

// ---------------------------------------------------------------------------
// K3: ball query. One wave per center. Exact f32 replication of
// d = ((-2*dot)+sc)+sx, mask d>0.04f, stable-(d,idx) 32-smallest, pad w/ first.
// ---------------------------------------------------------------------------
__global__ __launch_bounds__(256) void ballq_kernel(
    const float* __restrict__ X, const float* __restrict__ Y, const float* __restrict__ Z,
    const int* __restrict__ cidx, int* __restrict__ gidx) {
  __shared__ float dbuf[4][512];
  __shared__ int   ibuf[4][512];
  const int t = threadIdx.x;
  const int w = t >> 6, lane = t & 63;
  const int pc = blockIdx.x * 4 + w;               // 0..8191
  const int b = pc >> 10;
  const float* Xb = X + b * NPTS;
  const float* Yb = Y + b * NPTS;
  const float* Zb = Z + b * NPTS;
  const int cI = cidx[pc];
  const float cx = Xb[cI], cy = Yb[cI], cz = Zb[cI];
  const float sc = __fadd_rn(__fadd_rn(__fmul_rn(cx, cx), __fmul_rn(cy, cy)), __fmul_rn(cz, cz));
  const float R2 = 0.04f;                          // f32(0.2*0.2); below 0.04 -> same as np/jax
  int cnt = 0;                                     // wave-uniform
  for (int rr = 0; rr < 64; rr++) {
    int nI = rr * 64 + lane;
    float px = Xb[nI], py = Yb[nI], pz = Zb[nI];
    float dot = __fadd_rn(__fadd_rn(__fmul_rn(cx, px), __fmul_rn(cy, py)), __fmul_rn(cz, pz));
    float sx  = __fadd_rn(__fadd_rn(__fmul_rn(px, px), __fmul_rn(py, py)), __fmul_rn(pz, pz));
    float d   = __fadd_rn(__fadd_rn(__fmul_rn(-2.0f, dot), sc), sx);
    bool pred = !(d > R2);
    unsigned long long mask = __ballot(pred);
    if (pred) {
      int pos = cnt + (int)__popcll(mask & ((1ull << lane) - 1ull));
      if (pos < 512) { dbuf[w][pos] = d; ibuf[w][pos] = nI; }
    }
    cnt += (int)__popcll(mask);
  }
  const int K = cnt < 512 ? cnt : 512;
  float cd[8]; int ci[8];
  #pragma unroll
  for (int k = 0; k < 8; k++) {
    int pos = lane + 64 * k;
    if (pos < K) { cd[k] = dbuf[w][pos]; ci[k] = ibuf[w][pos]; }
    else         { cd[k] = INFINITY;     ci[k] = 0x7fffffff;  }
  }
  int first = 0;
  int* gout = gidx + pc * NSAMPLE;
  for (int it = 0; it < NSAMPLE; it++) {
    float bv = cd[0]; int bi = ci[0];
    #pragma unroll
    for (int k = 1; k < 8; k++)
      if (cd[k] < bv || (cd[k] == bv && ci[k] < bi)) { bv = cd[k]; bi = ci[k]; }
    #pragma unroll
    for (int off = 32; off >= 1; off >>= 1) {
      float ov = __shfl_xor(bv, off);
      int   oi = __shfl_xor(bi, off);
      if (ov < bv || (ov == bv && oi < bi)) { bv = ov; bi = oi; }
    }
    #pragma unroll
    for (int k = 0; k < 8; k++) if (ci[k] == bi) cd[k] = INFINITY;
    if (it == 0) first = bi;
    if (lane == 0) gout[it] = (it < K) ? bi : first;
  }
}

// ---------------------------------------------------------------------------
// K4: gather + attention. One block (256 thr) per center. Thread (n=t&31,
// q=t>>5) computes 16 logit channels; softmax over n via 32-lane shuffles.
// ---------------------------------------------------------------------------
__global__ __launch_bounds__(256, 3) void attn_kernel(
    const float* __restrict__ X, const float* __restrict__ Y, const float* __restrict__ Z,
    const float* __restrict__ mfeat, const int* __restrict__ cidx, const int* __restrict__ gidx,
    const float* __restrict__ a_att, float* __restrict__ out) {
  __shared__ float gf[NSAMPLE][PADG];              // gathered MLP feats
  __shared__ float delta[131][NSAMPLE];
  __shared__ float cf[128];
  __shared__ float gx[NSAMPLE], gy[NSAMPLE], gz[NSAMPLE];
  __shared__ float cxs[3];
  __shared__ int   gi_s[NSAMPLE];
  const int t = threadIdx.x;
  const int pc = blockIdx.x;                       // 0..8191
  const int b = pc >> 10;
  const int n = t & 31, q = t >> 5;                // q: 0..7, 16 channels each
  if (t < NSAMPLE) gi_s[t] = gidx[pc * NSAMPLE + t];
  const int cI = cidx[pc];
  if (t == 0) {
    cxs[0] = X[b * NPTS + cI]; cxs[1] = Y[b * NPTS + cI]; cxs[2] = Z[b * NPTS + cI];
  }
  if (t < 128) cf[t] = mfeat[((size_t)b * NPTS + cI) * 128 + t];
  __syncthreads();
  const int g = gi_s[n];
  const float* grow = mfeat + ((size_t)b * NPTS + g) * 128;
  #pragma unroll
  for (int k = 0; k < 4; k++) {
    float4 v = *(const float4*)(grow + q * 16 + 4 * k);
    *(float4*)&gf[n][q * 16 + 4 * k] = v;
  }
  if (t < NSAMPLE) {
    int gg = gi_s[t];
    gx[t] = X[b * NPTS + gg]; gy[t] = Y[b * NPTS + gg]; gz[t] = Z[b * NPTS + gg];
  }
  __syncthreads();
  if (t < NSAMPLE) {
    delta[0][t] = gx[t] - cxs[0];
    delta[1][t] = gy[t] - cxs[1];
    delta[2][t] = gz[t] - cxs[2];
  }
  #pragma unroll
  for (int k = 0; k < 16; k++) {
    int d = q * 16 + k;
    delta[3 + d][n] = gf[n][d] - cf[d];
  }
  __syncthreads();

  float acc[16];
  #pragma unroll
  for (int j = 0; j < 16; j++) acc[j] = 0.0f;
  for (int c = 0; c < 131; c++) {
    float dl = delta[c][n];                        // LDS broadcast
    const float* arow = a_att + c * 128 + q * 16;  // global, lane-dedup via cache
    #pragma unroll
    for (int k = 0; k < 4; k++) {
      float4 wv = *(const float4*)(arow + 4 * k);
      acc[4 * k + 0] = fmaf(dl, wv.x, acc[4 * k + 0]);
      acc[4 * k + 1] = fmaf(dl, wv.y, acc[4 * k + 1]);
      acc[4 * k + 2] = fmaf(dl, wv.z, acc[4 * k + 2]);
      acc[4 * k + 3] = fmaf(dl, wv.w, acc[4 * k + 3]);
    }
  }
  #pragma unroll
  for (int j = 0; j < 16; j++) acc[j] = acc[j] >= 0.0f ? acc[j] : 0.2f * acc[j];
  // softmax over n (32-lane subgroup; xor offsets <32 stay in group)
  float mx[16];
  #pragma unroll
  for (int j = 0; j < 16; j++) mx[j] = acc[j];
  #pragma unroll
  for (int off = 16; off >= 1; off >>= 1)
    #pragma unroll
    for (int j = 0; j < 16; j++) mx[j] = fmaxf(mx[j], __shfl_xor(mx[j], off));
  float e[16], s[16];
  #pragma unroll
  for (int j = 0; j < 16; j++) { e[j] = expf(acc[j] - mx[j]); s[j] = e[j]; }
  #pragma unroll
  for (int off = 16; off >= 1; off >>= 1)
    #pragma unroll
    for (int j = 0; j < 16; j++) s[j] += __shfl_xor(s[j], off);
  float gac[16];
  #pragma unroll
  for (int j = 0; j < 16; j++) gac[j] = (e[j] / s[j]) * gf[n][q * 16 + j];
  #pragma unroll
  for (int off = 16; off >= 1; off >>= 1)
    #pragma unroll
    for (int j = 0; j < 16; j++) gac[j] += __shfl_xor(gac[j], off);
  if (n == 0) {
    float* orow = out + (size_t)pc * 131;
    #pragma unroll
    for (int j = 0; j < 16; j++) orow[3 + q * 16 + j] = gac[j];
    if (q == 0) { orow[0] = cxs[0]; orow[1] = cxs[1]; orow[2] = cxs[2]; }
  }
}

// ---------------------------------------------------------------------------
extern "C" void kernel_launch(void* const* d_in, const int* in_sizes, int n_in,
                              void* d_out, int out_size, void* d_ws, size_t ws_size,
                              hipStream_t stream) {
  const float* points = (const float*)d_in[0];
  const float* W0 = (const float*)d_in[1];
  const float* B0 = (const float*)d_in[2];
  const float* G0 = (const float*)d_in[3];
  const float* E0 = (const float*)d_in[4];
  const float* W1 = (const float*)d_in[5];
  const float* B1 = (const float*)d_in[6];
  const float* G1 = (const float*)d_in[7];
  const float* E1 = (const float*)d_in[8];
  const float* W2 = (const float*)d_in[9];
  const float* B2 = (const float*)d_in[10];
  const float* G2 = (const float*)d_in[11];
  const float* E2 = (const float*)d_in[12];
  const float* Aatt = (const float*)d_in[13];
  float* out = (float*)d_out;

  // workspace layout (floats): mfeat | X | Y | Z | cidx | gidx  (~18.3 MB)
  float* mfeat = (float*)d_ws;
  float* Xw = mfeat + (size_t)NBATCH * NPTS * 128;
  float* Yw = Xw + NBATCH * NPTS;
  float* Zw = Yw + NBATCH * NPTS;
  int* cidxw = (int*)(Zw + NBATCH * NPTS);
  int* gidxw = cidxw + NBATCH * NPOINT;

  repack_kernel<<<NBATCH * NPTS / 256, 256, 0, stream>>>(points, Xw, Yw, Zw);
  fps_kernel<<<NBATCH, 512, 0, stream>>>(points, cidxw);
  mlp_kernel<<<NBATCH * NPTS / 256, 256, 0, stream>>>(points,
      W0, B0, G0, E0, W1, B1, G1, E1, W2, B2, G2, E2, mfeat);
  ballq_kernel<<<NBATCH * NPOINT / 4, 256, 0, stream>>>(Xw, Yw, Zw, cidxw, gidxw);
  attn_kernel<<<NBATCH * NPOINT, 256, 0, stream>>>(Xw, Yw, Zw, mfeat, cidxw, gidxw, Aatt, out);
}

// Round 3
// 1413.871 us; speedup vs baseline: 1.3203x; 1.2495x over previous
//
#include <hip/hip_runtime.h>
#include <math.h>

#define NBATCH 8
#define NPTS 4096
#define NPOINT 1024
#define NSAMPLE 32
#define PTDIM 67        // 3 xyz + 64 feat
#define BIGF 1e10f
#define PADG 132        // gfeat LDS row stride (128 + 4 pad)

// DPP ctrl encodings (gfx9/CDNA)
#define DPP_QUAD_XOR1 0xB1   // quad_perm [1,0,3,2]
#define DPP_QUAD_XOR2 0x4E   // quad_perm [2,3,0,1]
#define DPP_ROW_HALF_MIRROR 0x141
#define DPP_ROW_MIRROR 0x140
#define DPP_ROW_BCAST15 0x142
#define DPP_ROW_BCAST31 0x143

// one argmax-combine step over a DPP lane pattern; (hi,lo) is the packed key:
// hi = f32 bits of dist (>=0 so unsigned-monotone), lo = 4095-idx (bigger =
// smaller idx => first-index tie-break). Lanes with undefined DPP source get
// old (=self) -> no-op combine. VALU-only: no DS pipe on the reduce chain.
template <int CTRL>
__device__ inline void dpp_max2(unsigned& hi, unsigned& lo) {
  unsigned nh = (unsigned)__builtin_amdgcn_update_dpp((int)hi, (int)hi, CTRL, 0xf, 0xf, false);
  unsigned nl = (unsigned)__builtin_amdgcn_update_dpp((int)lo, (int)lo, CTRL, 0xf, 0xf, false);
  bool take = (nh > hi) || (nh == hi && nl > lo);
  hi = take ? nh : hi;
  lo = take ? nl : lo;
}

// ---------------------------------------------------------------------------
// K0: repack xyz into SoA for coalesced access in ball-query / attention
// ---------------------------------------------------------------------------
__global__ __launch_bounds__(256) void repack_kernel(const float* __restrict__ pts,
    float* __restrict__ X, float* __restrict__ Y, float* __restrict__ Z) {
  int i = blockIdx.x * 256 + threadIdx.x;          // < NBATCH*NPTS
  const float* p = pts + (size_t)i * PTDIM;
  X[i] = p[0]; Y[i] = p[1]; Z[i] = p[2];
}

// ---------------------------------------------------------------------------
// K1: farthest point sampling. One block per batch.
// v3: 256 threads (1 wave/SIMD, no VALU issue serialization), 16 pts/lane in
// VGPRs; wave argmax via VALU-only DPP ladder -> lane63 -> readlane (no DS
// shuffles); 4 cross-wave slots + ONE barrier/step; cidx buffered in LDS.
// Exact f32 replication of jnp: ((dx*dx+dy*dy)+dz*dz), min, argmax first-idx.
// ---------------------------------------------------------------------------
__global__ __launch_bounds__(256) void fps_kernel(const float* __restrict__ pts,
                                                  int* __restrict__ cidx) {
  __shared__ float Cx[NPTS], Cy[NPTS], Cz[NPTS];   // coords for center lookup
  __shared__ unsigned long long slots[2][4];
  __shared__ int cidxS[NPOINT];
  const int b = blockIdx.x, tid = threadIdx.x;
  const int w = tid >> 6, lane = tid & 63;
  const float* pb = pts + (size_t)b * NPTS * PTDIM;
  float px[16], py[16], pz[16], dl[16];
  #pragma unroll
  for (int k = 0; k < 16; k++) {
    int j = tid + (k << 8);
    const float* pj = pb + (size_t)j * PTDIM;
    float x = pj[0], y = pj[1], z = pj[2];
    px[k] = x; py[k] = y; pz[k] = z;
    Cx[j] = x; Cy[j] = y; Cz[j] = z;
    dl[k] = BIGF;
  }
  __syncthreads();
  int f = 0;
  float cx = Cx[0], cy = Cy[0], cz = Cz[0];
  for (int t = 0; t < NPOINT; t++) {
    if (tid == 0) cidxS[t] = f;                    // emit BEFORE update (scan semantics)
    float bv = -1.0f; int bi = 0;
    #pragma unroll
    for (int k = 0; k < 16; k++) {
      float dx = __fsub_rn(px[k], cx);
      float dy = __fsub_rn(py[k], cy);
      float dz = __fsub_rn(pz[k], cz);
      float d = __fadd_rn(__fadd_rn(__fmul_rn(dx, dx), __fmul_rn(dy, dy)), __fmul_rn(dz, dz));
      float nd = fminf(dl[k], d);
      dl[k] = nd;
      if (nd > bv) { bv = nd; bi = tid + (k << 8); }  // ascending j -> first-max kept
    }
    unsigned hi = __float_as_uint(bv);
    unsigned lo = (unsigned)(NPTS - 1 - bi);
    dpp_max2<DPP_QUAD_XOR1>(hi, lo);
    dpp_max2<DPP_QUAD_XOR2>(hi, lo);
    dpp_max2<DPP_ROW_HALF_MIRROR>(hi, lo);
    dpp_max2<DPP_ROW_MIRROR>(hi, lo);              // all lanes in row16 have row max
    dpp_max2<DPP_ROW_BCAST15>(hi, lo);             // row1 = max(r0,r1); row3 = max(r2,r3)
    dpp_max2<DPP_ROW_BCAST31>(hi, lo);             // lane63 = wave max
    unsigned ghi = (unsigned)__builtin_amdgcn_readlane((int)hi, 63);
    unsigned glo = (unsigned)__builtin_amdgcn_readlane((int)lo, 63);
    if (lane == 0)
      slots[t & 1][w] = ((unsigned long long)ghi << 32) | (unsigned long long)glo;
    __syncthreads();
    unsigned long long s0 = slots[t & 1][0], s1 = slots[t & 1][1];
    unsigned long long s2 = slots[t & 1][2], s3 = slots[t & 1][3];
    unsigned long long m0 = s0 > s1 ? s0 : s1;
    unsigned long long m1 = s2 > s3 ? s2 : s3;
    unsigned long long best = m0 > m1 ? m0 : m1;
    f = NPTS - 1 - (int)(best & 0xFFFFFFFFull);
    cx = Cx[f]; cy = Cy[f]; cz = Cz[f];            // same-address broadcast reads
  }
  __syncthreads();
  for (int i = tid; i < NPOINT; i += 256) cidx[b * NPOINT + i] = cidxS[i];
}

// ---------------------------------------------------------------------------
// K2: 3-layer MLP over ALL points (MLP∘gather == gather∘MLP). Thread-per-row,
// weights in LDS (broadcast reads), fully unrolled so x/h stay in VGPRs.
// ---------------------------------------------------------------------------
__global__ __launch_bounds__(256, 2) void mlp_kernel(
    const float* __restrict__ pts,
    const float* __restrict__ W0, const float* __restrict__ B0, const float* __restrict__ G0, const float* __restrict__ E0,
    const float* __restrict__ W1, const float* __restrict__ B1, const float* __restrict__ G1, const float* __restrict__ E1,
    const float* __restrict__ W2, const float* __restrict__ B2, const float* __restrict__ G2, const float* __restrict__ E2,
    float* __restrict__ mfeat) {
  __shared__ float w0[64 * 64], w1[64 * 64], w2[128 * 64];
  __shared__ float bb0[64], ss0[64], ee0[64];
  __shared__ float bb1[64], ss1[64], ee1[64];
  __shared__ float bb2[128], ss2[128], ee2[128];
  const float INVS = 0.99999500003750f;            // 1/sqrt(1+1e-5)
  const int t = threadIdx.x;
  for (int i = t; i < 4096; i += 256) { w0[i] = W0[i]; w1[i] = W1[i]; }
  for (int i = t; i < 8192; i += 256) { w2[i] = W2[i]; }
  if (t < 64) {
    bb0[t] = B0[t]; ss0[t] = G0[t] * INVS; ee0[t] = E0[t];
    bb1[t] = B1[t]; ss1[t] = G1[t] * INVS; ee1[t] = E1[t];
  }
  if (t < 128) { bb2[t] = B2[t]; ss2[t] = G2[t] * INVS; ee2[t] = E2[t]; }
  __syncthreads();

  const size_t r = (size_t)blockIdx.x * 256 + t;   // row 0..32767
  const float* xr = pts + r * PTDIM + 3;
  float x[64];
  #pragma unroll
  for (int c = 0; c < 64; c++) x[c] = xr[c];

  float h1[64];
  #pragma unroll
  for (int o = 0; o < 64; o++) {
    float acc = bb0[o];
    #pragma unroll
    for (int c = 0; c < 64; c += 4) {
      float4 wv = *(const float4*)&w0[o * 64 + c];
      acc = fmaf(wv.x, x[c], acc);
      acc = fmaf(wv.y, x[c + 1], acc);
      acc = fmaf(wv.z, x[c + 2], acc);
      acc = fmaf(wv.w, x[c + 3], acc);
    }
    h1[o] = fmaxf(fmaf(acc, ss0[o], ee0[o]), 0.0f);
  }
  float h2[64];
  #pragma unroll
  for (int o = 0; o < 64; o++) {
    float acc = bb1[o];
    #pragma unroll
    for (int c = 0; c < 64; c += 4) {
      float4 wv = *(const float4*)&w1[o * 64 + c];
      acc = fmaf(wv.x, h1[c], acc);
      acc = fmaf(wv.y, h1[c + 1], acc);
      acc = fmaf(wv.z, h1[c + 2], acc);
      acc = fmaf(wv.w, h1[c + 3], acc);
    }
    h2[o] = fmaxf(fmaf(acc, ss1[o], ee1[o]), 0.0f);
  }
  float* orow = mfeat + r * 128;
  #pragma unroll
  for (int o = 0; o < 128; o += 4) {
    float a0 = bb2[o], a1 = bb2[o + 1], a2 = bb2[o + 2], a3 = bb2[o + 3];
    #pragma unroll
    for (int c = 0; c < 64; c += 4) {
      float4 wv0 = *(const float4*)&w2[(o    ) * 64 + c];
      float4 wv1 = *(const float4*)&w2[(o + 1) * 64 + c];
      float4 wv2 = *(const float4*)&w2[(o + 2) * 64 + c];
      float4 wv3 = *(const float4*)&w2[(o + 3) * 64 + c];
      a0 = fmaf(wv0.x, h2[c], a0); a0 = fmaf(wv0.y, h2[c+1], a0); a0 = fmaf(wv0.z, h2[c+2], a0); a0 = fmaf(wv0.w, h2[c+3], a0);
      a1 = fmaf(wv1.x, h2[c], a1); a1 = fmaf(wv1.y, h2[c+1], a1); a1 = fmaf(wv1.z, h2[c+2], a1); a1 = fmaf(wv1.w, h2[c+3], a1);
      a2 = fmaf(wv2.x, h2[c], a2); a2 = fmaf(wv2.y, h2[c+1], a2); a2 = fmaf(wv2.z, h2[c+2], a2); a2 = fmaf(wv2.w, h2[c+3], a2);
      a3 = fmaf(wv3.x, h2[c], a3); a3 = fmaf(wv3.y, h2[c+1], a3); a3 = fmaf(wv3.z, h2[c+2], a3); a3 = fmaf(wv3.w, h2[c+3], a3);
    }
    float4 ov;
    ov.x = fmaxf(fmaf(a0, ss2[o    ], ee2[o    ]), 0.0f);
    ov.y = fmaxf(fmaf(a1, ss2[o + 1], ee2[o + 1]), 0.0f);
    ov.z = fmaxf(fmaf(a2, ss2[o + 2], ee2[o + 2]), 0.0f);
    ov.w = fmaxf(fmaf(a3, ss2[o + 3], ee2[o + 3]), 0.0f);
    *(float4*)(orow + o) = ov;
  }
}

// ---------------------------------------------------------------------------
// K3: ball query. One wave per center. Exact f32 replication of
// d = ((-2*dot)+sc)+sx, mask d>0.04f, stable-(d,idx) 32-smallest, pad w/ first.
// ---------------------------------------------------------------------------
__global__ __launch_bounds__(256) void ballq_kernel(
    const float* __restrict__ X, const float* __restrict__ Y, const float* __restrict__ Z,
    const int* __restrict__ cidx, int* __restrict__ gidx) {
  __shared__ float dbuf[4][512];
  __shared__ int   ibuf[4][512];
  const int t = threadIdx.x;
  const int w = t >> 6, lane = t & 63;
  const int pc = blockIdx.x * 4 + w;               // 0..8191
  const int b = pc >> 10;
  const float* Xb = X + b * NPTS;
  const float* Yb = Y + b * NPTS;
  const float* Zb = Z + b * NPTS;
  const int cI = cidx[pc];
  const float cx = Xb[cI], cy = Yb[cI], cz = Zb[cI];
  const float sc = __fadd_rn(__fadd_rn(__fmul_rn(cx, cx), __fmul_rn(cy, cy)), __fmul_rn(cz, cz));
  const float R2 = 0.04f;                          // f32(0.2*0.2); below 0.04 -> same as np/jax
  int cnt = 0;                                     // wave-uniform
  for (int rr = 0; rr < 64; rr++) {
    int nI = rr * 64 + lane;
    float px = Xb[nI], py = Yb[nI], pz = Zb[nI];
    float dot = __fadd_rn(__fadd_rn(__fmul_rn(cx, px), __fmul_rn(cy, py)), __fmul_rn(cz, pz));
    float sx  = __fadd_rn(__fadd_rn(__fmul_rn(px, px), __fmul_rn(py, py)), __fmul_rn(pz, pz));
    float d   = __fadd_rn(__fadd_rn(__fmul_rn(-2.0f, dot), sc), sx);
    bool pred = !(d > R2);
    unsigned long long mask = __ballot(pred);
    if (pred) {
      int pos = cnt + (int)__popcll(mask & ((1ull << lane) - 1ull));
      if (pos < 512) { dbuf[w][pos] = d; ibuf[w][pos] = nI; }
    }
    cnt += (int)__popcll(mask);
  }
  const int K = cnt < 512 ? cnt : 512;
  float cd[8]; int ci[8];
  #pragma unroll
  for (int k = 0; k < 8; k++) {
    int pos = lane + 64 * k;
    if (pos < K) { cd[k] = dbuf[w][pos]; ci[k] = ibuf[w][pos]; }
    else         { cd[k] = INFINITY;     ci[k] = 0x7fffffff;  }
  }
  int first = 0;
  int* gout = gidx + pc * NSAMPLE;
  for (int it = 0; it < NSAMPLE; it++) {
    float bv = cd[0]; int bi = ci[0];
    #pragma unroll
    for (int k = 1; k < 8; k++)
      if (cd[k] < bv || (cd[k] == bv && ci[k] < bi)) { bv = cd[k]; bi = ci[k]; }
    #pragma unroll
    for (int off = 32; off >= 1; off >>= 1) {
      float ov = __shfl_xor(bv, off);
      int   oi = __shfl_xor(bi, off);
      if (ov < bv || (ov == bv && oi < bi)) { bv = ov; bi = oi; }
    }
    #pragma unroll
    for (int k = 0; k < 8; k++) if (ci[k] == bi) cd[k] = INFINITY;
    if (it == 0) first = bi;
    if (lane == 0) gout[it] = (it < K) ? bi : first;
  }
}

// ---------------------------------------------------------------------------
// K4: gather + attention. One block (256 thr) per center. Thread (n=t&31,
// q=t>>5) computes 16 logit channels; softmax over n via 32-lane shuffles.
// ---------------------------------------------------------------------------
__global__ __launch_bounds__(256, 3) void attn_kernel(
    const float* __restrict__ X, const float* __restrict__ Y, const float* __restrict__ Z,
    const float* __restrict__ mfeat, const int* __restrict__ cidx, const int* __restrict__ gidx,
    const float* __restrict__ a_att, float* __restrict__ out) {
  __shared__ float gf[NSAMPLE][PADG];              // gathered MLP feats
  __shared__ float delta[131][NSAMPLE];
  __shared__ float cf[128];
  __shared__ float gx[NSAMPLE], gy[NSAMPLE], gz[NSAMPLE];
  __shared__ float cxs[3];
  __shared__ int   gi_s[NSAMPLE];
  const int t = threadIdx.x;
  const int pc = blockIdx.x;                       // 0..8191
  const int b = pc >> 10;
  const int n = t & 31, q = t >> 5;                // q: 0..7, 16 channels each
  if (t < NSAMPLE) gi_s[t] = gidx[pc * NSAMPLE + t];
  const int cI = cidx[pc];
  if (t == 0) {
    cxs[0] = X[b * NPTS + cI]; cxs[1] = Y[b * NPTS + cI]; cxs[2] = Z[b * NPTS + cI];
  }
  if (t < 128) cf[t] = mfeat[((size_t)b * NPTS + cI) * 128 + t];
  __syncthreads();
  const int g = gi_s[n];
  const float* grow = mfeat + ((size_t)b * NPTS + g) * 128;
  #pragma unroll
  for (int k = 0; k < 4; k++) {
    float4 v = *(const float4*)(grow + q * 16 + 4 * k);
    *(float4*)&gf[n][q * 16 + 4 * k] = v;
  }
  if (t < NSAMPLE) {
    int gg = gi_s[t];
    gx[t] = X[b * NPTS + gg]; gy[t] = Y[b * NPTS + gg]; gz[t] = Z[b * NPTS + gg];
  }
  __syncthreads();
  if (t < NSAMPLE) {
    delta[0][t] = gx[t] - cxs[0];
    delta[1][t] = gy[t] - cxs[1];
    delta[2][t] = gz[t] - cxs[2];
  }
  #pragma unroll
  for (int k = 0; k < 16; k++) {
    int d = q * 16 + k;
    delta[3 + d][n] = gf[n][d] - cf[d];
  }
  __syncthreads();

  float acc[16];
  #pragma unroll
  for (int j = 0; j < 16; j++) acc[j] = 0.0f;
  for (int c = 0; c < 131; c++) {
    float dl = delta[c][n];                        // LDS broadcast
    const float* arow = a_att + c * 128 + q * 16;  // global, lane-dedup via cache
    #pragma unroll
    for (int k = 0; k < 4; k++) {
      float4 wv = *(const float4*)(arow + 4 * k);
      acc[4 * k + 0] = fmaf(dl, wv.x, acc[4 * k + 0]);
      acc[4 * k + 1] = fmaf(dl, wv.y, acc[4 * k + 1]);
      acc[4 * k + 2] = fmaf(dl, wv.z, acc[4 * k + 2]);
      acc[4 * k + 3] = fmaf(dl, wv.w, acc[4 * k + 3]);
    }
  }
  #pragma unroll
  for (int j = 0; j < 16; j++) acc[j] = acc[j] >= 0.0f ? acc[j] : 0.2f * acc[j];
  // softmax over n (32-lane subgroup; xor offsets <32 stay in group)
  float mx[16];
  #pragma unroll
  for (int j = 0; j < 16; j++) mx[j] = acc[j];
  #pragma unroll
  for (int off = 16; off >= 1; off >>= 1)
    #pragma unroll
    for (int j = 0; j < 16; j++) mx[j] = fmaxf(mx[j], __shfl_xor(mx[j], off));
  float e[16], s[16];
  #pragma unroll
  for (int j = 0; j < 16; j++) { e[j] = expf(acc[j] - mx[j]); s[j] = e[j]; }
  #pragma unroll
  for (int off = 16; off >= 1; off >>= 1)
    #pragma unroll
    for (int j = 0; j < 16; j++) s[j] += __shfl_xor(s[j], off);
  float gac[16];
  #pragma unroll
  for (int j = 0; j < 16; j++) gac[j] = (e[j] / s[j]) * gf[n][q * 16 + j];
  #pragma unroll
  for (int off = 16; off >= 1; off >>= 1)
    #pragma unroll
    for (int j = 0; j < 16; j++) gac[j] += __shfl_xor(gac[j], off);
  if (n == 0) {
    float* orow = out + (size_t)pc * 131;
    #pragma unroll
    for (int j = 0; j < 16; j++) orow[3 + q * 16 + j] = gac[j];
    if (q == 0) { orow[0] = cxs[0]; orow[1] = cxs[1]; orow[2] = cxs[2]; }
  }
}

// ---------------------------------------------------------------------------
extern "C" void kernel_launch(void* const* d_in, const int* in_sizes, int n_in,
                              void* d_out, int out_size, void* d_ws, size_t ws_size,
                              hipStream_t stream) {
  const float* points = (const float*)d_in[0];
  const float* W0 = (const float*)d_in[1];
  const float* B0 = (const float*)d_in[2];
  const float* G0 = (const float*)d_in[3];
  const float* E0 = (const float*)d_in[4];
  const float* W1 = (const float*)d_in[5];
  const float* B1 = (const float*)d_in[6];
  const float* G1 = (const float*)d_in[7];
  const float* E1 = (const float*)d_in[8];
  const float* W2 = (const float*)d_in[9];
  const float* B2 = (const float*)d_in[10];
  const float* G2 = (const float*)d_in[11];
  const float* E2 = (const float*)d_in[12];
  const float* Aatt = (const float*)d_in[13];
  float* out = (float*)d_out;

  // workspace layout (floats): mfeat | X | Y | Z | cidx | gidx  (~18.3 MB)
  float* mfeat = (float*)d_ws;
  float* Xw = mfeat + (size_t)NBATCH * NPTS * 128;
  float* Yw = Xw + NBATCH * NPTS;
  float* Zw = Yw + NBATCH * NPTS;
  int* cidxw = (int*)(Zw + NBATCH * NPTS);
  int* gidxw = cidxw + NBATCH * NPOINT;

  repack_kernel<<<NBATCH * NPTS / 256, 256, 0, stream>>>(points, Xw, Yw, Zw);
  fps_kernel<<<NBATCH, 256, 0, stream>>>(points, cidxw);
  mlp_kernel<<<NBATCH * NPTS / 256, 256, 0, stream>>>(points,
      W0, B0, G0, E0, W1, B1, G1, E1, W2, B2, G2, E2, mfeat);
  ballq_kernel<<<NBATCH * NPOINT / 4, 256, 0, stream>>>(Xw, Yw, Zw, cidxw, gidxw);
  attn_kernel<<<NBATCH * NPOINT, 256, 0, stream>>>(Xw, Yw, Zw, mfeat, cidxw, gidxw, Aatt, out);
}

// Round 4
// 1015.517 us; speedup vs baseline: 1.8382x; 1.3923x over previous
//
#include <hip/hip_runtime.h>
#include <math.h>

#define NBATCH 8
#define NPTS 4096
#define NPOINT 1024
#define NSAMPLE 32
#define PTDIM 67        // 3 xyz + 64 feat
#define BIGF 1e10f

// DPP ctrl encodings (gfx9/CDNA)
#define DPP_QUAD_XOR1 0xB1   // quad_perm [1,0,3,2]
#define DPP_QUAD_XOR2 0x4E   // quad_perm [2,3,0,1]
#define DPP_ROW_HALF_MIRROR 0x141
#define DPP_ROW_MIRROR 0x140
#define DPP_ROW_BCAST15 0x142
#define DPP_ROW_BCAST31 0x143

template <int CTRL>
__device__ inline void dpp_max2(unsigned& hi, unsigned& lo) {
  unsigned nh = (unsigned)__builtin_amdgcn_update_dpp((int)hi, (int)hi, CTRL, 0xf, 0xf, false);
  unsigned nl = (unsigned)__builtin_amdgcn_update_dpp((int)lo, (int)lo, CTRL, 0xf, 0xf, false);
  bool take = (nh > hi) || (nh == hi && nl > lo);
  hi = take ? nh : hi;
  lo = take ? nl : lo;
}

// ---------------------------------------------------------------------------
// F1: fused FPS (blocks 0..7; also emits SoA xyz, replacing repack) + MLP
// (blocks 8..135). LDS overlaid via char buffer (max of the two layouts =
// 68608 B, same as the previously-working mlp kernel).
// ---------------------------------------------------------------------------
struct FpsS {
  unsigned long long slots[2][4];
  int cidxS[NPOINT];
  float Cx[NPTS], Cy[NPTS], Cz[NPTS];
};
struct MlpS {
  float w0[64 * 64], w1[64 * 64], w2[128 * 64];
  float bb0[64], ss0[64], ee0[64];
  float bb1[64], ss1[64], ee1[64];
  float bb2[128], ss2[128], ee2[128];
};
#define F1_SMEM (sizeof(MlpS) > sizeof(FpsS) ? sizeof(MlpS) : sizeof(FpsS))

// FPS: one block per batch, 256 thr, 16 pts/lane in VGPRs; DPP u64 argmax
// ladder -> lane63 -> readlane; 4 cross-wave slots + ONE barrier/step.
// Exact f32 replication of jnp: ((dx*dx+dy*dy)+dz*dz), min, argmax first-idx.
__device__ void fps_body(char* smemRaw, const float* __restrict__ pts,
                         int* __restrict__ cidx, float* __restrict__ X,
                         float* __restrict__ Y, float* __restrict__ Z) {
  FpsS* S = (FpsS*)smemRaw;
  const int b = blockIdx.x, tid = threadIdx.x;
  const int w = tid >> 6, lane = tid & 63;
  const float* pb = pts + (size_t)b * NPTS * PTDIM;
  float px[16], py[16], pz[16], dl[16];
  #pragma unroll
  for (int k = 0; k < 16; k++) {
    int j = tid + (k << 8);
    const float* pj = pb + (size_t)j * PTDIM;
    float x = pj[0], y = pj[1], z = pj[2];
    px[k] = x; py[k] = y; pz[k] = z;
    S->Cx[j] = x; S->Cy[j] = y; S->Cz[j] = z;
    X[b * NPTS + j] = x; Y[b * NPTS + j] = y; Z[b * NPTS + j] = z;  // SoA out
    dl[k] = BIGF;
  }
  __syncthreads();
  int f = 0;
  float cx = S->Cx[0], cy = S->Cy[0], cz = S->Cz[0];
  for (int t = 0; t < NPOINT; t++) {
    if (tid == 0) S->cidxS[t] = f;                 // emit BEFORE update
    float bv = -1.0f; int bi = 0;
    #pragma unroll
    for (int k = 0; k < 16; k++) {
      float dx = __fsub_rn(px[k], cx);
      float dy = __fsub_rn(py[k], cy);
      float dz = __fsub_rn(pz[k], cz);
      float d = __fadd_rn(__fadd_rn(__fmul_rn(dx, dx), __fmul_rn(dy, dy)), __fmul_rn(dz, dz));
      float nd = fminf(dl[k], d);
      dl[k] = nd;
      if (nd > bv) { bv = nd; bi = tid + (k << 8); }  // ascending j -> first-max
    }
    unsigned hi = __float_as_uint(bv);
    unsigned lo = (unsigned)(NPTS - 1 - bi);
    dpp_max2<DPP_QUAD_XOR1>(hi, lo);
    dpp_max2<DPP_QUAD_XOR2>(hi, lo);
    dpp_max2<DPP_ROW_HALF_MIRROR>(hi, lo);
    dpp_max2<DPP_ROW_MIRROR>(hi, lo);
    dpp_max2<DPP_ROW_BCAST15>(hi, lo);
    dpp_max2<DPP_ROW_BCAST31>(hi, lo);
    unsigned ghi = (unsigned)__builtin_amdgcn_readlane((int)hi, 63);
    unsigned glo = (unsigned)__builtin_amdgcn_readlane((int)lo, 63);
    if (lane == 0)
      S->slots[t & 1][w] = ((unsigned long long)ghi << 32) | (unsigned long long)glo;
    __syncthreads();
    unsigned long long s0 = S->slots[t & 1][0], s1 = S->slots[t & 1][1];
    unsigned long long s2 = S->slots[t & 1][2], s3 = S->slots[t & 1][3];
    unsigned long long m0 = s0 > s1 ? s0 : s1;
    unsigned long long m1 = s2 > s3 ? s2 : s3;
    unsigned long long best = m0 > m1 ? m0 : m1;
    f = NPTS - 1 - (int)(best & 0xFFFFFFFFull);
    cx = S->Cx[f]; cy = S->Cy[f]; cz = S->Cz[f];   // same-addr broadcast reads
  }
  __syncthreads();
  for (int i = tid; i < NPOINT; i += 256) cidx[b * NPOINT + i] = S->cidxS[i];
}

// MLP over ALL points (MLP∘gather == gather∘MLP). Thread-per-row, weights in
// LDS (broadcast reads), fully unrolled so x/h stay in VGPRs.
__device__ void mlp_body(char* smemRaw, const float* __restrict__ pts,
    const float* __restrict__ W0, const float* __restrict__ B0, const float* __restrict__ G0, const float* __restrict__ E0,
    const float* __restrict__ W1, const float* __restrict__ B1, const float* __restrict__ G1, const float* __restrict__ E1,
    const float* __restrict__ W2, const float* __restrict__ B2, const float* __restrict__ G2, const float* __restrict__ E2,
    float* __restrict__ mfeat) {
  MlpS* S = (MlpS*)smemRaw;
  const float INVS = 0.99999500003750f;            // 1/sqrt(1+1e-5)
  const int t = threadIdx.x;
  for (int i = t; i < 4096; i += 256) { S->w0[i] = W0[i]; S->w1[i] = W1[i]; }
  for (int i = t; i < 8192; i += 256) { S->w2[i] = W2[i]; }
  if (t < 64) {
    S->bb0[t] = B0[t]; S->ss0[t] = G0[t] * INVS; S->ee0[t] = E0[t];
    S->bb1[t] = B1[t]; S->ss1[t] = G1[t] * INVS; S->ee1[t] = E1[t];
  }
  if (t < 128) { S->bb2[t] = B2[t]; S->ss2[t] = G2[t] * INVS; S->ee2[t] = E2[t]; }
  __syncthreads();

  const size_t r = (size_t)(blockIdx.x - 8) * 256 + t;   // row 0..32767
  const float* xr = pts + r * PTDIM + 3;
  float x[64];
  #pragma unroll
  for (int c = 0; c < 64; c++) x[c] = xr[c];

  float h1[64];
  #pragma unroll
  for (int o = 0; o < 64; o++) {
    float acc = S->bb0[o];
    #pragma unroll
    for (int c = 0; c < 64; c += 4) {
      float4 wv = *(const float4*)&S->w0[o * 64 + c];
      acc = fmaf(wv.x, x[c], acc);
      acc = fmaf(wv.y, x[c + 1], acc);
      acc = fmaf(wv.z, x[c + 2], acc);
      acc = fmaf(wv.w, x[c + 3], acc);
    }
    h1[o] = fmaxf(fmaf(acc, S->ss0[o], S->ee0[o]), 0.0f);
  }
  float h2[64];
  #pragma unroll
  for (int o = 0; o < 64; o++) {
    float acc = S->bb1[o];
    #pragma unroll
    for (int c = 0; c < 64; c += 4) {
      float4 wv = *(const float4*)&S->w1[o * 64 + c];
      acc = fmaf(wv.x, h1[c], acc);
      acc = fmaf(wv.y, h1[c + 1], acc);
      acc = fmaf(wv.z, h1[c + 2], acc);
      acc = fmaf(wv.w, h1[c + 3], acc);
    }
    h2[o] = fmaxf(fmaf(acc, S->ss1[o], S->ee1[o]), 0.0f);
  }
  float* orow = mfeat + r * 128;
  #pragma unroll
  for (int o = 0; o < 128; o += 4) {
    float a0 = S->bb2[o], a1 = S->bb2[o + 1], a2 = S->bb2[o + 2], a3 = S->bb2[o + 3];
    #pragma unroll
    for (int c = 0; c < 64; c += 4) {
      float4 wv0 = *(const float4*)&S->w2[(o    ) * 64 + c];
      float4 wv1 = *(const float4*)&S->w2[(o + 1) * 64 + c];
      float4 wv2 = *(const float4*)&S->w2[(o + 2) * 64 + c];
      float4 wv3 = *(const float4*)&S->w2[(o + 3) * 64 + c];
      a0 = fmaf(wv0.x, h2[c], a0); a0 = fmaf(wv0.y, h2[c+1], a0); a0 = fmaf(wv0.z, h2[c+2], a0); a0 = fmaf(wv0.w, h2[c+3], a0);
      a1 = fmaf(wv1.x, h2[c], a1); a1 = fmaf(wv1.y, h2[c+1], a1); a1 = fmaf(wv1.z, h2[c+2], a1); a1 = fmaf(wv1.w, h2[c+3], a1);
      a2 = fmaf(wv2.x, h2[c], a2); a2 = fmaf(wv2.y, h2[c+1], a2); a2 = fmaf(wv2.z, h2[c+2], a2); a2 = fmaf(wv2.w, h2[c+3], a2);
      a3 = fmaf(wv3.x, h2[c], a3); a3 = fmaf(wv3.y, h2[c+1], a3); a3 = fmaf(wv3.z, h2[c+2], a3); a3 = fmaf(wv3.w, h2[c+3], a3);
    }
    float4 ov;
    ov.x = fmaxf(fmaf(a0, S->ss2[o    ], S->ee2[o    ]), 0.0f);
    ov.y = fmaxf(fmaf(a1, S->ss2[o + 1], S->ee2[o + 1]), 0.0f);
    ov.z = fmaxf(fmaf(a2, S->ss2[o + 2], S->ee2[o + 2]), 0.0f);
    ov.w = fmaxf(fmaf(a3, S->ss2[o + 3], S->ee2[o + 3]), 0.0f);
    *(float4*)(orow + o) = ov;
  }
}

__global__ __launch_bounds__(256) void f1_kernel(const float* __restrict__ pts,
    const float* __restrict__ W0, const float* __restrict__ B0, const float* __restrict__ G0, const float* __restrict__ E0,
    const float* __restrict__ W1, const float* __restrict__ B1, const float* __restrict__ G1, const float* __restrict__ E1,
    const float* __restrict__ W2, const float* __restrict__ B2, const float* __restrict__ G2, const float* __restrict__ E2,
    float* __restrict__ mfeat, int* __restrict__ cidx,
    float* __restrict__ X, float* __restrict__ Y, float* __restrict__ Z) {
  __shared__ __align__(16) char smem[F1_SMEM];
  if (blockIdx.x < 8)
    fps_body(smem, pts, cidx, X, Y, Z);
  else
    mlp_body(smem, pts, W0, B0, G0, E0, W1, B1, G1, E1, W2, B2, G2, E2, mfeat);
}

// ---------------------------------------------------------------------------
// F2: fused ball-query (blocks 0..2047) + attention projection P = [xyz,f]@A
// (blocks 2048..2303). Independent given F1's outputs.
// ---------------------------------------------------------------------------
__device__ void ballq_body(const float* __restrict__ X, const float* __restrict__ Y,
                           const float* __restrict__ Z, const int* __restrict__ cidx,
                           int* __restrict__ gidx,
                           float (*dbuf)[512], int (*ibuf)[512]) {
  const int t = threadIdx.x;
  const int w = t >> 6, lane = t & 63;
  const int pc = blockIdx.x * 4 + w;               // 0..8191
  const int b = pc >> 10;
  const float* Xb = X + b * NPTS;
  const float* Yb = Y + b * NPTS;
  const float* Zb = Z + b * NPTS;
  const int cI = cidx[pc];
  const float cx = Xb[cI], cy = Yb[cI], cz = Zb[cI];
  const float sc = __fadd_rn(__fadd_rn(__fmul_rn(cx, cx), __fmul_rn(cy, cy)), __fmul_rn(cz, cz));
  const float R2 = 0.04f;
  int cnt = 0;                                     // wave-uniform
  for (int rr = 0; rr < 64; rr++) {
    int nI = rr * 64 + lane;
    float px = Xb[nI], py = Yb[nI], pz = Zb[nI];
    float dot = __fadd_rn(__fadd_rn(__fmul_rn(cx, px), __fmul_rn(cy, py)), __fmul_rn(cz, pz));
    float sx  = __fadd_rn(__fadd_rn(__fmul_rn(px, px), __fmul_rn(py, py)), __fmul_rn(pz, pz));
    float d   = __fadd_rn(__fadd_rn(__fmul_rn(-2.0f, dot), sc), sx);
    bool pred = !(d > R2);
    unsigned long long mask = __ballot(pred);
    if (pred) {
      int pos = cnt + (int)__popcll(mask & ((1ull << lane) - 1ull));
      if (pos < 512) { dbuf[w][pos] = d; ibuf[w][pos] = nI; }
    }
    cnt += (int)__popcll(mask);
  }
  const int K = cnt < 512 ? cnt : 512;
  float cd[8]; int ci[8];
  #pragma unroll
  for (int k = 0; k < 8; k++) {
    int pos = lane + 64 * k;
    if (pos < K) { cd[k] = dbuf[w][pos]; ci[k] = ibuf[w][pos]; }
    else         { cd[k] = INFINITY;     ci[k] = 0x7fffffff;  }
  }
  int first = 0;
  int* gout = gidx + pc * NSAMPLE;
  for (int it = 0; it < NSAMPLE; it++) {
    float bv = cd[0]; int bi = ci[0];
    #pragma unroll
    for (int k = 1; k < 8; k++)
      if (cd[k] < bv || (cd[k] == bv && ci[k] < bi)) { bv = cd[k]; bi = ci[k]; }
    #pragma unroll
    for (int off = 32; off >= 1; off >>= 1) {
      float ov = __shfl_xor(bv, off);
      int   oi = __shfl_xor(bi, off);
      if (ov < bv || (ov == bv && oi < bi)) { bv = ov; bi = oi; }
    }
    #pragma unroll
    for (int k = 0; k < 8; k++) if (ci[k] == bi) cd[k] = INFINITY;
    if (it == 0) first = bi;
    if (lane == 0) gout[it] = (it < K) ? bi : first;
  }
}

// P projection: block = (row-tile of 512) x (col-group of 32). Each thread
// computes 2 rows x 32 cols; A col-slice staged in LDS (broadcast b128 reads).
__device__ void proj_body(const float* __restrict__ X, const float* __restrict__ Y,
                          const float* __restrict__ Z, const float* __restrict__ mfeat,
                          const float* __restrict__ Aatt, float* __restrict__ P,
                          float* As /* [131*32] */) {
  const int t = threadIdx.x;
  const int pb = blockIdx.x - 2048;                // 0..255
  const int grp = pb & 3;                          // col group: cols grp*32..+32
  const int tile = pb >> 2;                        // 0..63 -> rows tile*512..+512
  for (int i = t; i < 131 * 32; i += 256) {
    int c = i >> 5, col = i & 31;
    As[i] = Aatt[c * 128 + grp * 32 + col];
  }
  __syncthreads();
  const int r0 = tile * 512 + t * 2;               // rows r0, r0+1
  float acc0[32], acc1[32];
  {
    float x0 = X[r0], y0 = Y[r0], z0 = Z[r0];
    float x1 = X[r0 + 1], y1 = Y[r0 + 1], z1 = Z[r0 + 1];
    #pragma unroll
    for (int j = 0; j < 32; j += 4) {
      float4 a0 = *(const float4*)&As[0 * 32 + j];
      float4 a1 = *(const float4*)&As[1 * 32 + j];
      float4 a2 = *(const float4*)&As[2 * 32 + j];
      acc0[j]   = fmaf(z0, a2.x, fmaf(y0, a1.x, x0 * a0.x));
      acc0[j+1] = fmaf(z0, a2.y, fmaf(y0, a1.y, x0 * a0.y));
      acc0[j+2] = fmaf(z0, a2.z, fmaf(y0, a1.z, x0 * a0.z));
      acc0[j+3] = fmaf(z0, a2.w, fmaf(y0, a1.w, x0 * a0.w));
      acc1[j]   = fmaf(z1, a2.x, fmaf(y1, a1.x, x1 * a0.x));
      acc1[j+1] = fmaf(z1, a2.y, fmaf(y1, a1.y, x1 * a0.y));
      acc1[j+2] = fmaf(z1, a2.z, fmaf(y1, a1.z, x1 * a0.z));
      acc1[j+3] = fmaf(z1, a2.w, fmaf(y1, a1.w, x1 * a0.w));
    }
  }
  const float* m0 = mfeat + (size_t)r0 * 128;
  const float* m1 = m0 + 128;
  for (int c = 0; c < 128; c += 4) {
    float4 v0 = *(const float4*)(m0 + c);
    float4 v1 = *(const float4*)(m1 + c);
    #pragma unroll
    for (int u = 0; u < 4; u++) {
      const float* arow = &As[(3 + c + u) * 32];
      float s0 = u == 0 ? v0.x : u == 1 ? v0.y : u == 2 ? v0.z : v0.w;
      float s1 = u == 0 ? v1.x : u == 1 ? v1.y : u == 2 ? v1.z : v1.w;
      #pragma unroll
      for (int j = 0; j < 32; j += 4) {
        float4 a = *(const float4*)&arow[j];
        acc0[j]   = fmaf(s0, a.x, acc0[j]);
        acc0[j+1] = fmaf(s0, a.y, acc0[j+1]);
        acc0[j+2] = fmaf(s0, a.z, acc0[j+2]);
        acc0[j+3] = fmaf(s0, a.w, acc0[j+3]);
        acc1[j]   = fmaf(s1, a.x, acc1[j]);
        acc1[j+1] = fmaf(s1, a.y, acc1[j+1]);
        acc1[j+2] = fmaf(s1, a.z, acc1[j+2]);
        acc1[j+3] = fmaf(s1, a.w, acc1[j+3]);
      }
    }
  }
  float* p0 = P + (size_t)r0 * 128 + grp * 32;
  float* p1 = p0 + 128;
  #pragma unroll
  for (int j = 0; j < 32; j += 4) {
    *(float4*)(p0 + j) = make_float4(acc0[j], acc0[j+1], acc0[j+2], acc0[j+3]);
    *(float4*)(p1 + j) = make_float4(acc1[j], acc1[j+1], acc1[j+2], acc1[j+3]);
  }
}

__global__ __launch_bounds__(256) void f2_kernel(
    const float* __restrict__ X, const float* __restrict__ Y, const float* __restrict__ Z,
    const int* __restrict__ cidx, int* __restrict__ gidx,
    const float* __restrict__ mfeat, const float* __restrict__ Aatt,
    float* __restrict__ P) {
  __shared__ float dbuf[4][512];
  __shared__ int   ibuf[4][512];
  __shared__ float As[131 * 32];
  if (blockIdx.x < 2048)
    ballq_body(X, Y, Z, cidx, gidx, dbuf, ibuf);
  else
    proj_body(X, Y, Z, mfeat, Aatt, P, As);
}

// ---------------------------------------------------------------------------
// F3: attention-lite. logits = P[g] - P[c] (projection identity), leaky,
// softmax over n via 32-lane shuffles, weighted gfeat sum. Zero LDS; block
// per center; XCD-swizzled so each batch's P/mfeat slice stays in one L2.
// ---------------------------------------------------------------------------
__global__ __launch_bounds__(256) void attn_kernel(
    const float* __restrict__ X, const float* __restrict__ Y, const float* __restrict__ Z,
    const float* __restrict__ mfeat, const float* __restrict__ P,
    const int* __restrict__ cidx, const int* __restrict__ gidx,
    float* __restrict__ out) {
  const int pc = (blockIdx.x & 7) * 1024 + (blockIdx.x >> 3);  // batch-per-XCD
  const int b = pc >> 10;
  const int t = threadIdx.x;
  const int n = t & 31, q = t >> 5;                // q: 0..7, 16 channels each
  const int cI = cidx[pc];
  const int g = gidx[pc * NSAMPLE + n];
  const float* Pg = P + ((size_t)b * NPTS + g) * 128 + q * 16;
  const float* Pc = P + ((size_t)b * NPTS + cI) * 128 + q * 16;
  const float* Gf = mfeat + ((size_t)b * NPTS + g) * 128 + q * 16;
  float a[16], gfv[16];
  #pragma unroll
  for (int k = 0; k < 4; k++) {
    float4 vg = *(const float4*)(Pg + 4 * k);
    float4 vc = *(const float4*)(Pc + 4 * k);
    float4 vf = *(const float4*)(Gf + 4 * k);
    a[4*k]   = vg.x - vc.x; a[4*k+1] = vg.y - vc.y;
    a[4*k+2] = vg.z - vc.z; a[4*k+3] = vg.w - vc.w;
    gfv[4*k] = vf.x; gfv[4*k+1] = vf.y; gfv[4*k+2] = vf.z; gfv[4*k+3] = vf.w;
  }
  #pragma unroll
  for (int j = 0; j < 16; j++) a[j] = a[j] >= 0.0f ? a[j] : 0.2f * a[j];
  // softmax over n (32-lane subgroup; xor offsets <32 stay in group)
  float mx[16];
  #pragma unroll
  for (int j = 0; j < 16; j++) mx[j] = a[j];
  #pragma unroll
  for (int off = 16; off >= 1; off >>= 1)
    #pragma unroll
    for (int j = 0; j < 16; j++) mx[j] = fmaxf(mx[j], __shfl_xor(mx[j], off));
  float e[16], s[16];
  #pragma unroll
  for (int j = 0; j < 16; j++) { e[j] = expf(a[j] - mx[j]); s[j] = e[j]; }
  #pragma unroll
  for (int off = 16; off >= 1; off >>= 1)
    #pragma unroll
    for (int j = 0; j < 16; j++) s[j] += __shfl_xor(s[j], off);
  float gac[16];
  #pragma unroll
  for (int j = 0; j < 16; j++) gac[j] = (e[j] / s[j]) * gfv[j];
  #pragma unroll
  for (int off = 16; off >= 1; off >>= 1)
    #pragma unroll
    for (int j = 0; j < 16; j++) gac[j] += __shfl_xor(gac[j], off);
  if (n == 0) {
    float* orow = out + (size_t)pc * 131;
    #pragma unroll
    for (int j = 0; j < 16; j++) orow[3 + q * 16 + j] = gac[j];
    if (q == 0) {
      orow[0] = X[b * NPTS + cI]; orow[1] = Y[b * NPTS + cI]; orow[2] = Z[b * NPTS + cI];
    }
  }
}

// ---------------------------------------------------------------------------
extern "C" void kernel_launch(void* const* d_in, const int* in_sizes, int n_in,
                              void* d_out, int out_size, void* d_ws, size_t ws_size,
                              hipStream_t stream) {
  const float* points = (const float*)d_in[0];
  const float* W0 = (const float*)d_in[1];
  const float* B0 = (const float*)d_in[2];
  const float* G0 = (const float*)d_in[3];
  const float* E0 = (const float*)d_in[4];
  const float* W1 = (const float*)d_in[5];
  const float* B1 = (const float*)d_in[6];
  const float* G1 = (const float*)d_in[7];
  const float* E1 = (const float*)d_in[8];
  const float* W2 = (const float*)d_in[9];
  const float* B2 = (const float*)d_in[10];
  const float* G2 = (const float*)d_in[11];
  const float* E2 = (const float*)d_in[12];
  const float* Aatt = (const float*)d_in[13];
  float* out = (float*)d_out;

  // workspace (floats): mfeat 4.19M | P 4.19M | X/Y/Z 3*32k | cidx 8k | gidx 256k  (~35 MB)
  float* mfeat = (float*)d_ws;
  float* Pw = mfeat + (size_t)NBATCH * NPTS * 128;
  float* Xw = Pw + (size_t)NBATCH * NPTS * 128;
  float* Yw = Xw + NBATCH * NPTS;
  float* Zw = Yw + NBATCH * NPTS;
  int* cidxw = (int*)(Zw + NBATCH * NPTS);
  int* gidxw = cidxw + NBATCH * NPOINT;

  f1_kernel<<<8 + NBATCH * NPTS / 256, 256, 0, stream>>>(points,
      W0, B0, G0, E0, W1, B1, G1, E1, W2, B2, G2, E2, mfeat, cidxw, Xw, Yw, Zw);
  f2_kernel<<<2048 + 256, 256, 0, stream>>>(Xw, Yw, Zw, cidxw, gidxw, mfeat, Aatt, Pw);
  attn_kernel<<<NBATCH * NPOINT, 256, 0, stream>>>(Xw, Yw, Zw, mfeat, Pw, cidxw, gidxw, out);
}

// Round 5
// 928.549 us; speedup vs baseline: 2.0103x; 1.0937x over previous
//
#include <hip/hip_runtime.h>
#include <math.h>

#define NBATCH 8
#define NPTS 4096
#define NPOINT 1024
#define NSAMPLE 32
#define PTDIM 67        // 3 xyz + 64 feat
#define BIGF 1e10f

// DPP ctrl encodings (gfx9/CDNA)
#define DPP_QUAD_XOR1 0xB1   // quad_perm [1,0,3,2]
#define DPP_QUAD_XOR2 0x4E   // quad_perm [2,3,0,1]
#define DPP_ROW_HALF_MIRROR 0x141
#define DPP_ROW_MIRROR 0x140
#define DPP_ROW_BCAST15 0x142
#define DPP_ROW_BCAST31 0x143

// self-as-old DPP moves: un-sourced lanes keep self -> combine is a no-op there
template <int CTRL>
__device__ inline float dpp_mov_f(float v) {
  int i = __float_as_int(v);
  return __int_as_float(__builtin_amdgcn_update_dpp(i, i, CTRL, 0xf, 0xf, false));
}
template <int CTRL>
__device__ inline unsigned dpp_mov_u(unsigned v) {
  return (unsigned)__builtin_amdgcn_update_dpp((int)v, (int)v, CTRL, 0xf, 0xf, false);
}
// lexicographic u64 (hi,lo) min combine over a DPP pattern (VALU-only)
template <int CTRL>
__device__ inline void dpp_min2(unsigned& hi, unsigned& lo) {
  unsigned nh = dpp_mov_u<CTRL>(hi);
  unsigned nl = dpp_mov_u<CTRL>(lo);
  bool take = (nh < hi) || (nh == hi && nl < lo);
  hi = take ? nh : hi;
  lo = take ? nl : lo;
}
// monotone map f32 -> u32 (ascending order preserved, incl. negatives)
__device__ inline unsigned fmap(float d) {
  unsigned b = __float_as_uint(d);
  return ((int)b < 0) ? ~b : (b | 0x80000000u);
}
#define FMAP_INF 0xFF800000u   // fmap(+INF)

// ---------------------------------------------------------------------------
// F1: fused FPS (blocks 0..7; also emits SoA xyz) + MLP (blocks 8..135).
// LDS overlaid via char buffer.
// ---------------------------------------------------------------------------
struct FpsS {
  unsigned long long slots[2][4];
  int cidxS[NPOINT];
  float4 C[NPTS];                                  // packed coords: 1 b128/lookup
};
struct MlpS {
  float w0[64 * 64], w1[64 * 64], w2[128 * 64];
  float bb0[64], ss0[64], ee0[64];
  float bb1[64], ss1[64], ee1[64];
  float bb2[128], ss2[128], ee2[128];
};
#define F1_SMEM (sizeof(MlpS) > sizeof(FpsS) ? sizeof(MlpS) : sizeof(FpsS))

// FPS: one block per batch, 256 thr, 16 pts/lane in VGPRs. Split-phase wave
// reduce: v_max_f32-DPP ladder (wave max dist) -> readlane63 -> v_min_u32-DPP
// ladder (min j among max lanes) -> readlane63. 4 cross-wave u64 slots + ONE
// barrier/step; center coords via single ds_read_b128.
// Exact f32 replication of jnp: ((dx*dx+dy*dy)+dz*dz), min, argmax first-idx.
// (bit-equality qualify is exact: sums of squares never produce -0)
__device__ void fps_body(char* smemRaw, const float* __restrict__ pts,
                         int* __restrict__ cidx, float* __restrict__ X,
                         float* __restrict__ Y, float* __restrict__ Z) {
  FpsS* S = (FpsS*)smemRaw;
  const int b = blockIdx.x, tid = threadIdx.x;
  const int w = tid >> 6, lane = tid & 63;
  const float* pb = pts + (size_t)b * NPTS * PTDIM;
  float px[16], py[16], pz[16], dl[16];
  #pragma unroll
  for (int k = 0; k < 16; k++) {
    int j = tid + (k << 8);
    const float* pj = pb + (size_t)j * PTDIM;
    float x = pj[0], y = pj[1], z = pj[2];
    px[k] = x; py[k] = y; pz[k] = z;
    S->C[j] = make_float4(x, y, z, 0.0f);
    X[b * NPTS + j] = x; Y[b * NPTS + j] = y; Z[b * NPTS + j] = z;  // SoA out
    dl[k] = BIGF;
  }
  __syncthreads();
  int f = 0;
  float4 c0 = S->C[0];
  float cx = c0.x, cy = c0.y, cz = c0.z;
  for (int t = 0; t < NPOINT; t++) {
    if (tid == 0) S->cidxS[t] = f;                 // emit BEFORE update
    float bv = -1.0f; int bi = 0;
    #pragma unroll
    for (int k = 0; k < 16; k++) {
      float dx = __fsub_rn(px[k], cx);
      float dy = __fsub_rn(py[k], cy);
      float dz = __fsub_rn(pz[k], cz);
      float d = __fadd_rn(__fadd_rn(__fmul_rn(dx, dx), __fmul_rn(dy, dy)), __fmul_rn(dz, dz));
      float nd = fminf(dl[k], d);
      dl[k] = nd;
      if (nd > bv) { bv = nd; bi = tid + (k << 8); }  // ascending j -> first-max
    }
    // phase 1: wave max of bv (2 instr/level)
    float m = bv;
    m = fmaxf(m, dpp_mov_f<DPP_QUAD_XOR1>(m));
    m = fmaxf(m, dpp_mov_f<DPP_QUAD_XOR2>(m));
    m = fmaxf(m, dpp_mov_f<DPP_ROW_HALF_MIRROR>(m));
    m = fmaxf(m, dpp_mov_f<DPP_ROW_MIRROR>(m));
    m = fmaxf(m, dpp_mov_f<DPP_ROW_BCAST15>(m));
    m = fmaxf(m, dpp_mov_f<DPP_ROW_BCAST31>(m));   // lane63 = wave max
    unsigned wmaxbits = (unsigned)__builtin_amdgcn_readlane(__float_as_int(m), 63);
    // phase 2: min index among lanes holding the max
    unsigned cand = (__float_as_uint(bv) == wmaxbits) ? (unsigned)bi : 0xFFFFFFFFu;
    cand = min(cand, dpp_mov_u<DPP_QUAD_XOR1>(cand));
    cand = min(cand, dpp_mov_u<DPP_QUAD_XOR2>(cand));
    cand = min(cand, dpp_mov_u<DPP_ROW_HALF_MIRROR>(cand));
    cand = min(cand, dpp_mov_u<DPP_ROW_MIRROR>(cand));
    cand = min(cand, dpp_mov_u<DPP_ROW_BCAST15>(cand));
    cand = min(cand, dpp_mov_u<DPP_ROW_BCAST31>(cand));  // lane63 = min j
    unsigned jmin = (unsigned)__builtin_amdgcn_readlane((int)cand, 63);
    if (lane == 0)
      S->slots[t & 1][w] = ((unsigned long long)wmaxbits << 32) |
                           (unsigned long long)(NPTS - 1 - jmin);  // bigger = smaller idx
    __syncthreads();
    unsigned long long s0 = S->slots[t & 1][0], s1 = S->slots[t & 1][1];
    unsigned long long s2 = S->slots[t & 1][2], s3 = S->slots[t & 1][3];
    unsigned long long m0 = s0 > s1 ? s0 : s1;
    unsigned long long m1 = s2 > s3 ? s2 : s3;
    unsigned long long best = m0 > m1 ? m0 : m1;
    f = NPTS - 1 - (int)(best & 0xFFFFFFFFull);
    float4 cc = S->C[f];                           // ONE b128 same-addr broadcast
    cx = cc.x; cy = cc.y; cz = cc.z;
  }
  __syncthreads();
  for (int i = tid; i < NPOINT; i += 256) cidx[b * NPOINT + i] = S->cidxS[i];
}

// MLP over ALL points (MLP∘gather == gather∘MLP). Thread-per-row, weights in
// LDS (broadcast reads), fully unrolled so x/h stay in VGPRs.
__device__ void mlp_body(char* smemRaw, const float* __restrict__ pts,
    const float* __restrict__ W0, const float* __restrict__ B0, const float* __restrict__ G0, const float* __restrict__ E0,
    const float* __restrict__ W1, const float* __restrict__ B1, const float* __restrict__ G1, const float* __restrict__ E1,
    const float* __restrict__ W2, const float* __restrict__ B2, const float* __restrict__ G2, const float* __restrict__ E2,
    float* __restrict__ mfeat) {
  MlpS* S = (MlpS*)smemRaw;
  const float INVS = 0.99999500003750f;            // 1/sqrt(1+1e-5)
  const int t = threadIdx.x;
  for (int i = t; i < 4096; i += 256) { S->w0[i] = W0[i]; S->w1[i] = W1[i]; }
  for (int i = t; i < 8192; i += 256) { S->w2[i] = W2[i]; }
  if (t < 64) {
    S->bb0[t] = B0[t]; S->ss0[t] = G0[t] * INVS; S->ee0[t] = E0[t];
    S->bb1[t] = B1[t]; S->ss1[t] = G1[t] * INVS; S->ee1[t] = E1[t];
  }
  if (t < 128) { S->bb2[t] = B2[t]; S->ss2[t] = G2[t] * INVS; S->ee2[t] = E2[t]; }
  __syncthreads();

  const size_t r = (size_t)(blockIdx.x - 8) * 256 + t;   // row 0..32767
  const float* xr = pts + r * PTDIM + 3;
  float x[64];
  #pragma unroll
  for (int c = 0; c < 64; c++) x[c] = xr[c];

  float h1[64];
  #pragma unroll
  for (int o = 0; o < 64; o++) {
    float acc = S->bb0[o];
    #pragma unroll
    for (int c = 0; c < 64; c += 4) {
      float4 wv = *(const float4*)&S->w0[o * 64 + c];
      acc = fmaf(wv.x, x[c], acc);
      acc = fmaf(wv.y, x[c + 1], acc);
      acc = fmaf(wv.z, x[c + 2], acc);
      acc = fmaf(wv.w, x[c + 3], acc);
    }
    h1[o] = fmaxf(fmaf(acc, S->ss0[o], S->ee0[o]), 0.0f);
  }
  float h2[64];
  #pragma unroll
  for (int o = 0; o < 64; o++) {
    float acc = S->bb1[o];
    #pragma unroll
    for (int c = 0; c < 64; c += 4) {
      float4 wv = *(const float4*)&S->w1[o * 64 + c];
      acc = fmaf(wv.x, h1[c], acc);
      acc = fmaf(wv.y, h1[c + 1], acc);
      acc = fmaf(wv.z, h1[c + 2], acc);
      acc = fmaf(wv.w, h1[c + 3], acc);
    }
    h2[o] = fmaxf(fmaf(acc, S->ss1[o], S->ee1[o]), 0.0f);
  }
  float* orow = mfeat + r * 128;
  #pragma unroll
  for (int o = 0; o < 128; o += 4) {
    float a0 = S->bb2[o], a1 = S->bb2[o + 1], a2 = S->bb2[o + 2], a3 = S->bb2[o + 3];
    #pragma unroll
    for (int c = 0; c < 64; c += 4) {
      float4 wv0 = *(const float4*)&S->w2[(o    ) * 64 + c];
      float4 wv1 = *(const float4*)&S->w2[(o + 1) * 64 + c];
      float4 wv2 = *(const float4*)&S->w2[(o + 2) * 64 + c];
      float4 wv3 = *(const float4*)&S->w2[(o + 3) * 64 + c];
      a0 = fmaf(wv0.x, h2[c], a0); a0 = fmaf(wv0.y, h2[c+1], a0); a0 = fmaf(wv0.z, h2[c+2], a0); a0 = fmaf(wv0.w, h2[c+3], a0);
      a1 = fmaf(wv1.x, h2[c], a1); a1 = fmaf(wv1.y, h2[c+1], a1); a1 = fmaf(wv1.z, h2[c+2], a1); a1 = fmaf(wv1.w, h2[c+3], a1);
      a2 = fmaf(wv2.x, h2[c], a2); a2 = fmaf(wv2.y, h2[c+1], a2); a2 = fmaf(wv2.z, h2[c+2], a2); a2 = fmaf(wv2.w, h2[c+3], a2);
      a3 = fmaf(wv3.x, h2[c], a3); a3 = fmaf(wv3.y, h2[c+1], a3); a3 = fmaf(wv3.z, h2[c+2], a3); a3 = fmaf(wv3.w, h2[c+3], a3);
    }
    float4 ov;
    ov.x = fmaxf(fmaf(a0, S->ss2[o    ], S->ee2[o    ]), 0.0f);
    ov.y = fmaxf(fmaf(a1, S->ss2[o + 1], S->ee2[o + 1]), 0.0f);
    ov.z = fmaxf(fmaf(a2, S->ss2[o + 2], S->ee2[o + 2]), 0.0f);
    ov.w = fmaxf(fmaf(a3, S->ss2[o + 3], S->ee2[o + 3]), 0.0f);
    *(float4*)(orow + o) = ov;
  }
}

__global__ __launch_bounds__(256) void f1_kernel(const float* __restrict__ pts,
    const float* __restrict__ W0, const float* __restrict__ B0, const float* __restrict__ G0, const float* __restrict__ E0,
    const float* __restrict__ W1, const float* __restrict__ B1, const float* __restrict__ G1, const float* __restrict__ E1,
    const float* __restrict__ W2, const float* __restrict__ B2, const float* __restrict__ G2, const float* __restrict__ E2,
    float* __restrict__ mfeat, int* __restrict__ cidx,
    float* __restrict__ X, float* __restrict__ Y, float* __restrict__ Z) {
  __shared__ __align__(16) char smem[F1_SMEM];
  if (blockIdx.x < 8)
    fps_body(smem, pts, cidx, X, Y, Z);
  else
    mlp_body(smem, pts, W0, B0, G0, E0, W1, B1, G1, E1, W2, B2, G2, E2, mfeat);
}

// ---------------------------------------------------------------------------
// F2: fused ball-query (blocks 0..2047) + attention projection P = [xyz,f]@A
// (blocks 2048..2303). Independent given F1's outputs.
// ---------------------------------------------------------------------------
// Ball query: one wave per center. Exact f32 replication of
// d = ((-2*dot)+sc)+sx, mask d>0.04f, stable-(d,idx) 32-smallest, pad w/ first.
// Extraction uses u64 (mapped-d, idx) keys + VALU-only DPP min ladder: no
// DS-pipe swizzles on the 32-iteration dependent chain.
__device__ void ballq_body(const float* __restrict__ X, const float* __restrict__ Y,
                           const float* __restrict__ Z, const int* __restrict__ cidx,
                           int* __restrict__ gidx,
                           float (*dbuf)[512], int (*ibuf)[512]) {
  const int t = threadIdx.x;
  const int w = t >> 6, lane = t & 63;
  const int pc = blockIdx.x * 4 + w;               // 0..8191
  const int b = pc >> 10;
  const float* Xb = X + b * NPTS;
  const float* Yb = Y + b * NPTS;
  const float* Zb = Z + b * NPTS;
  const int cI = cidx[pc];
  const float cx = Xb[cI], cy = Yb[cI], cz = Zb[cI];
  const float sc = __fadd_rn(__fadd_rn(__fmul_rn(cx, cx), __fmul_rn(cy, cy)), __fmul_rn(cz, cz));
  const float R2 = 0.04f;
  int cnt = 0;                                     // wave-uniform
  for (int rr = 0; rr < 64; rr++) {
    int nI = rr * 64 + lane;
    float px = Xb[nI], py = Yb[nI], pz = Zb[nI];
    float dot = __fadd_rn(__fadd_rn(__fmul_rn(cx, px), __fmul_rn(cy, py)), __fmul_rn(cz, pz));
    float sx  = __fadd_rn(__fadd_rn(__fmul_rn(px, px), __fmul_rn(py, py)), __fmul_rn(pz, pz));
    float d   = __fadd_rn(__fadd_rn(__fmul_rn(-2.0f, dot), sc), sx);
    bool pred = !(d > R2);
    unsigned long long mask = __ballot(pred);
    if (pred) {
      int pos = cnt + (int)__popcll(mask & ((1ull << lane) - 1ull));
      if (pos < 512) { dbuf[w][pos] = d; ibuf[w][pos] = nI; }
    }
    cnt += (int)__popcll(mask);
  }
  const int K = cnt < 512 ? cnt : 512;
  // u64 keys: hi = monotone-mapped d, lo = idx  ->  min key = (d,idx)-lex min
  unsigned long long kk[8];
  #pragma unroll
  for (int k = 0; k < 8; k++) {
    int pos = lane + 64 * k;
    if (pos < K)
      kk[k] = ((unsigned long long)fmap(dbuf[w][pos]) << 32) | (unsigned)ibuf[w][pos];
    else
      kk[k] = ((unsigned long long)FMAP_INF << 32) | 0x7fffffffu;
  }
  int first = 0;
  int* gout = gidx + pc * NSAMPLE;
  for (int it = 0; it < NSAMPLE; it++) {
    unsigned long long best = kk[0];
    #pragma unroll
    for (int k = 1; k < 8; k++) if (kk[k] < best) best = kk[k];
    unsigned hi = (unsigned)(best >> 32), lo = (unsigned)best;
    dpp_min2<DPP_QUAD_XOR1>(hi, lo);
    dpp_min2<DPP_QUAD_XOR2>(hi, lo);
    dpp_min2<DPP_ROW_HALF_MIRROR>(hi, lo);
    dpp_min2<DPP_ROW_MIRROR>(hi, lo);
    dpp_min2<DPP_ROW_BCAST15>(hi, lo);
    dpp_min2<DPP_ROW_BCAST31>(hi, lo);             // lane63 = wave min
    unsigned blo = (unsigned)__builtin_amdgcn_readlane((int)lo, 63);
    // remove: set d to +INF, keep idx (indices unique among valid entries)
    #pragma unroll
    for (int k = 0; k < 8; k++)
      if ((unsigned)kk[k] == blo)
        kk[k] = (kk[k] & 0xFFFFFFFFull) | ((unsigned long long)FMAP_INF << 32);
    if (it == 0) first = (int)blo;
    if (lane == 0) gout[it] = (it < K) ? (int)blo : first;
  }
}

// P projection: block = (row-tile of 512) x (col-group of 32). Each thread
// computes 2 rows x 32 cols; A col-slice staged in LDS (broadcast b128 reads).
__device__ void proj_body(const float* __restrict__ X, const float* __restrict__ Y,
                          const float* __restrict__ Z, const float* __restrict__ mfeat,
                          const float* __restrict__ Aatt, float* __restrict__ P,
                          float* As /* [131*32] */) {
  const int t = threadIdx.x;
  const int pb = blockIdx.x - 2048;                // 0..255
  const int grp = pb & 3;                          // col group: cols grp*32..+32
  const int tile = pb >> 2;                        // 0..63 -> rows tile*512..+512
  for (int i = t; i < 131 * 32; i += 256) {
    int c = i >> 5, col = i & 31;
    As[i] = Aatt[c * 128 + grp * 32 + col];
  }
  __syncthreads();
  const int r0 = tile * 512 + t * 2;               // rows r0, r0+1
  float acc0[32], acc1[32];
  {
    float x0 = X[r0], y0 = Y[r0], z0 = Z[r0];
    float x1 = X[r0 + 1], y1 = Y[r0 + 1], z1 = Z[r0 + 1];
    #pragma unroll
    for (int j = 0; j < 32; j += 4) {
      float4 a0 = *(const float4*)&As[0 * 32 + j];
      float4 a1 = *(const float4*)&As[1 * 32 + j];
      float4 a2 = *(const float4*)&As[2 * 32 + j];
      acc0[j]   = fmaf(z0, a2.x, fmaf(y0, a1.x, x0 * a0.x));
      acc0[j+1] = fmaf(z0, a2.y, fmaf(y0, a1.y, x0 * a0.y));
      acc0[j+2] = fmaf(z0, a2.z, fmaf(y0, a1.z, x0 * a0.z));
      acc0[j+3] = fmaf(z0, a2.w, fmaf(y0, a1.w, x0 * a0.w));
      acc1[j]   = fmaf(z1, a2.x, fmaf(y1, a1.x, x1 * a0.x));
      acc1[j+1] = fmaf(z1, a2.y, fmaf(y1, a1.y, x1 * a0.y));
      acc1[j+2] = fmaf(z1, a2.z, fmaf(y1, a1.z, x1 * a0.z));
      acc1[j+3] = fmaf(z1, a2.w, fmaf(y1, a1.w, x1 * a0.w));
    }
  }
  const float* m0 = mfeat + (size_t)r0 * 128;
  const float* m1 = m0 + 128;
  for (int c = 0; c < 128; c += 4) {
    float4 v0 = *(const float4*)(m0 + c);
    float4 v1 = *(const float4*)(m1 + c);
    #pragma unroll
    for (int u = 0; u < 4; u++) {
      const float* arow = &As[(3 + c + u) * 32];
      float s0 = u == 0 ? v0.x : u == 1 ? v0.y : u == 2 ? v0.z : v0.w;
      float s1 = u == 0 ? v1.x : u == 1 ? v1.y : u == 2 ? v1.z : v1.w;
      #pragma unroll
      for (int j = 0; j < 32; j += 4) {
        float4 a = *(const float4*)&arow[j];
        acc0[j]   = fmaf(s0, a.x, acc0[j]);
        acc0[j+1] = fmaf(s0, a.y, acc0[j+1]);
        acc0[j+2] = fmaf(s0, a.z, acc0[j+2]);
        acc0[j+3] = fmaf(s0, a.w, acc0[j+3]);
        acc1[j]   = fmaf(s1, a.x, acc1[j]);
        acc1[j+1] = fmaf(s1, a.y, acc1[j+1]);
        acc1[j+2] = fmaf(s1, a.z, acc1[j+2]);
        acc1[j+3] = fmaf(s1, a.w, acc1[j+3]);
      }
    }
  }
  float* p0 = P + (size_t)r0 * 128 + grp * 32;
  float* p1 = p0 + 128;
  #pragma unroll
  for (int j = 0; j < 32; j += 4) {
    *(float4*)(p0 + j) = make_float4(acc0[j], acc0[j+1], acc0[j+2], acc0[j+3]);
    *(float4*)(p1 + j) = make_float4(acc1[j], acc1[j+1], acc1[j+2], acc1[j+3]);
  }
}

__global__ __launch_bounds__(256) void f2_kernel(
    const float* __restrict__ X, const float* __restrict__ Y, const float* __restrict__ Z,
    const int* __restrict__ cidx, int* __restrict__ gidx,
    const float* __restrict__ mfeat, const float* __restrict__ Aatt,
    float* __restrict__ P) {
  __shared__ float dbuf[4][512];
  __shared__ int   ibuf[4][512];
  __shared__ float As[131 * 32];
  if (blockIdx.x < 2048)
    ballq_body(X, Y, Z, cidx, gidx, dbuf, ibuf);
  else
    proj_body(X, Y, Z, mfeat, Aatt, P, As);
}

// ---------------------------------------------------------------------------
// F3: attention-lite. logits = P[g] - P[c] (projection identity), leaky,
// softmax over n via 32-lane shuffles, weighted gfeat sum. Zero LDS; block
// per center; XCD-swizzled so each batch's P/mfeat slice stays in one L2.
// ---------------------------------------------------------------------------
__global__ __launch_bounds__(256) void attn_kernel(
    const float* __restrict__ X, const float* __restrict__ Y, const float* __restrict__ Z,
    const float* __restrict__ mfeat, const float* __restrict__ P,
    const int* __restrict__ cidx, const int* __restrict__ gidx,
    float* __restrict__ out) {
  const int pc = (blockIdx.x & 7) * 1024 + (blockIdx.x >> 3);  // batch-per-XCD
  const int b = pc >> 10;
  const int t = threadIdx.x;
  const int n = t & 31, q = t >> 5;                // q: 0..7, 16 channels each
  const int cI = cidx[pc];
  const int g = gidx[pc * NSAMPLE + n];
  const float* Pg = P + ((size_t)b * NPTS + g) * 128 + q * 16;
  const float* Pc = P + ((size_t)b * NPTS + cI) * 128 + q * 16;
  const float* Gf = mfeat + ((size_t)b * NPTS + g) * 128 + q * 16;
  float a[16], gfv[16];
  #pragma unroll
  for (int k = 0; k < 4; k++) {
    float4 vg = *(const float4*)(Pg + 4 * k);
    float4 vc = *(const float4*)(Pc + 4 * k);
    float4 vf = *(const float4*)(Gf + 4 * k);
    a[4*k]   = vg.x - vc.x; a[4*k+1] = vg.y - vc.y;
    a[4*k+2] = vg.z - vc.z; a[4*k+3] = vg.w - vc.w;
    gfv[4*k] = vf.x; gfv[4*k+1] = vf.y; gfv[4*k+2] = vf.z; gfv[4*k+3] = vf.w;
  }
  #pragma unroll
  for (int j = 0; j < 16; j++) a[j] = a[j] >= 0.0f ? a[j] : 0.2f * a[j];
  // softmax over n (32-lane subgroup; xor offsets <32 stay in group)
  float mx[16];
  #pragma unroll
  for (int j = 0; j < 16; j++) mx[j] = a[j];
  #pragma unroll
  for (int off = 16; off >= 1; off >>= 1)
    #pragma unroll
    for (int j = 0; j < 16; j++) mx[j] = fmaxf(mx[j], __shfl_xor(mx[j], off));
  float e[16], s[16];
  #pragma unroll
  for (int j = 0; j < 16; j++) { e[j] = expf(a[j] - mx[j]); s[j] = e[j]; }
  #pragma unroll
  for (int off = 16; off >= 1; off >>= 1)
    #pragma unroll
    for (int j = 0; j < 16; j++) s[j] += __shfl_xor(s[j], off);
  float gac[16];
  #pragma unroll
  for (int j = 0; j < 16; j++) gac[j] = (e[j] / s[j]) * gfv[j];
  #pragma unroll
  for (int off = 16; off >= 1; off >>= 1)
    #pragma unroll
    for (int j = 0; j < 16; j++) gac[j] += __shfl_xor(gac[j], off);
  if (n == 0) {
    float* orow = out + (size_t)pc * 131;
    #pragma unroll
    for (int j = 0; j < 16; j++) orow[3 + q * 16 + j] = gac[j];
    if (q == 0) {
      orow[0] = X[b * NPTS + cI]; orow[1] = Y[b * NPTS + cI]; orow[2] = Z[b * NPTS + cI];
    }
  }
}

// ---------------------------------------------------------------------------
extern "C" void kernel_launch(void* const* d_in, const int* in_sizes, int n_in,
                              void* d_out, int out_size, void* d_ws, size_t ws_size,
                              hipStream_t stream) {
  const float* points = (const float*)d_in[0];
  const float* W0 = (const float*)d_in[1];
  const float* B0 = (const float*)d_in[2];
  const float* G0 = (const float*)d_in[3];
  const float* E0 = (const float*)d_in[4];
  const float* W1 = (const float*)d_in[5];
  const float* B1 = (const float*)d_in[6];
  const float* G1 = (const float*)d_in[7];
  const float* E1 = (const float*)d_in[8];
  const float* W2 = (const float*)d_in[9];
  const float* B2 = (const float*)d_in[10];
  const float* G2 = (const float*)d_in[11];
  const float* E2 = (const float*)d_in[12];
  const float* Aatt = (const float*)d_in[13];
  float* out = (float*)d_out;

  // workspace (floats): mfeat 4.19M | P 4.19M | X/Y/Z 3*32k | cidx 8k | gidx 256k  (~35 MB)
  float* mfeat = (float*)d_ws;
  float* Pw = mfeat + (size_t)NBATCH * NPTS * 128;
  float* Xw = Pw + (size_t)NBATCH * NPTS * 128;
  float* Yw = Xw + NBATCH * NPTS;
  float* Zw = Yw + NBATCH * NPTS;
  int* cidxw = (int*)(Zw + NBATCH * NPTS);
  int* gidxw = cidxw + NBATCH * NPOINT;

  f1_kernel<<<8 + NBATCH * NPTS / 256, 256, 0, stream>>>(points,
      W0, B0, G0, E0, W1, B1, G1, E1, W2, B2, G2, E2, mfeat, cidxw, Xw, Yw, Zw);
  f2_kernel<<<2048 + 256, 256, 0, stream>>>(Xw, Yw, Zw, cidxw, gidxw, mfeat, Aatt, Pw);
  attn_kernel<<<NBATCH * NPOINT, 256, 0, stream>>>(Xw, Yw, Zw, mfeat, Pw, cidxw, gidxw, out);
}